// Round 4
// baseline (848.840 us; speedup 1.0000x reference)
//
#include <hip/hip_runtime.h>
#include <hip/hip_bf16.h>

// ---------------------------------------------------------------------------
// Single fused persistent kernel (NORMAL launch, graph-capture-safe), grid
// 256 x 256 thr (>=1 block/CU guaranteed resident; LDS 30KB -> >=2/CU
// capacity), phases separated by a software sense-reversal grid barrier with
// device-scope atomics + threadfence (cross-XCD safe, Guideline 16).
// Phases:
//  P0 convert X -> Xhi/Xlo bf16 planes
//  P1 L1 gemm (3-split MFMA, 32x8 tiles)   P2 reduce+lrelu -> h1 planes
//  P3 L2 gemm (16x16)                      P4 reduce -> h2 planes
//  P5 L3 gemm (16x16, kchunk 64)           P6 reduce -> feat[:, :1024] + h3hi
//  P7 gemm4 full-K (160 blocks) -> accM bf16 128x10240
//  P8 pairwise (2 o's per block) -> feat[:, 1024:]
//  P9 final_dot (128 blocks)
// ws layout (bytes):
//   [0, 8388608)        P fp32 partials (max 16x128x1024x4) / accM bf16 (2.6MB)
//   [8388608 .. )       Xhi,Xlo,h1hi,h1lo (512KB each), h2hi,h2lo,h3hi (256KB)
//   [11272192,12058624) feat 128x1536 f32
// ---------------------------------------------------------------------------

typedef __bf16 bf16x8 __attribute__((ext_vector_type(8)));
typedef __bf16 bf16x2 __attribute__((ext_vector_type(2)));
typedef float  f32x4  __attribute__((ext_vector_type(4)));

#define OFF_XHI  8388608
#define OFF_XLO  8912896
#define OFF_H1HI 9437184
#define OFF_H1LO 9961472
#define OFF_H2HI 10485760
#define OFF_H2LO 10747904
#define OFF_H3HI 11010048
#define OFF_FEAT 11272192

#define NBLK 256

// grid-barrier state: module globals, zero-initialized at load; barrier
// protocol leaves cnt==0 after each use and only ever increments gen, so
// graph replays need no reset.
__device__ unsigned g_cnt = 0;
__device__ unsigned g_gen = 0;

static __device__ __forceinline__ void gbar(int t) {
  __threadfence();                      // drain + writeback this thread's stores
  __syncthreads();
  if (t == 0) {
    unsigned g = __hip_atomic_load(&g_gen, __ATOMIC_RELAXED, __HIP_MEMORY_SCOPE_AGENT);
    unsigned a = __hip_atomic_fetch_add(&g_cnt, 1u, __ATOMIC_ACQ_REL,
                                        __HIP_MEMORY_SCOPE_AGENT);
    if (a + 1u == NBLK) {
      __hip_atomic_store(&g_cnt, 0u, __ATOMIC_RELAXED, __HIP_MEMORY_SCOPE_AGENT);
      __hip_atomic_store(&g_gen, g + 1u, __ATOMIC_RELEASE, __HIP_MEMORY_SCOPE_AGENT);
    } else {
      // bounded spin: bail after ~1e8 cycles instead of wedging the container
      for (unsigned it = 0; it < (1u << 27); ++it) {
        if (__hip_atomic_load(&g_gen, __ATOMIC_ACQUIRE, __HIP_MEMORY_SCOPE_AGENT) != g)
          break;
        __builtin_amdgcn_s_sleep(1);
      }
    }
  }
  __syncthreads();
  __threadfence();                      // acquire side: invalidate stale caches
}

static __device__ __forceinline__ unsigned int f2bf(float f) {
  union { float f; unsigned int u; } v; v.f = f;
  unsigned int r = v.u + 0x7FFFu + ((v.u >> 16) & 1u);   // RNE to bf16
  return r >> 16;
}
static __device__ __forceinline__ float bf2f(unsigned short u) {
  union { unsigned int u; float f; } v; v.u = ((unsigned int)u) << 16;
  return v.f;
}
static __device__ __forceinline__ unsigned int pack_bf16_rne(float a, float b) {
  bf16x2 v; v[0] = (__bf16)a; v[1] = (__bf16)b;
  return __builtin_bit_cast(unsigned int, v);
}
static __device__ __forceinline__ float lrelu(float x) {
  return x >= 0.0f ? x : 0.01f * x;
}

// ---------------------------------------------------------------------------
// P0: X fp32 -> hi/lo bf16 split planes. 32768 active threads x 8 elems.
// ---------------------------------------------------------------------------
static __device__ __forceinline__ void convert_body(
    const float* __restrict__ X, unsigned short* __restrict__ Hi,
    unsigned short* __restrict__ Lo, int g)
{
  if (g >= 32768) return;
  float a[8];
  *(float4*)(a + 0) = *(const float4*)(X + (size_t)g * 8);
  *(float4*)(a + 4) = *(const float4*)(X + (size_t)g * 8 + 4);
  unsigned int hu[4], lu[4];
  #pragma unroll
  for (int i = 0; i < 4; i++) {
    float x0 = a[2 * i], x1 = a[2 * i + 1];
    unsigned int h = pack_bf16_rne(x0, x1);
    float f0 = bf2f((unsigned short)(h & 0xFFFFu));
    float f1 = bf2f((unsigned short)(h >> 16));
    hu[i] = h;
    lu[i] = pack_bf16_rne(x0 - f0, x1 - f1);
  }
  *(uint4*)(Hi + (size_t)g * 8) = *(uint4*)hu;
  *(uint4*)(Lo + (size_t)g * 8) = *(uint4*)lu;
}

// ---------------------------------------------------------------------------
// Dense-layer GEMM, 3-split bf16 MFMA: C = Ahi*Whi + Ahi*Wlo + Alo*Whi.
// Tile 128x64, k-tile 32, split-K partials into P. smem: 30720 B.
// ---------------------------------------------------------------------------
static __device__ __forceinline__ void gemm3_body(
    const unsigned short* __restrict__ Ahi, const unsigned short* __restrict__ Alo,
    const float* __restrict__ W, float* __restrict__ P,
    int K, int N, int kchunk, int bx, int by, int t, char* smem)
{
  unsigned short* AHs = (unsigned short*)smem;            // [128][40]
  unsigned short* ALs = (unsigned short*)(smem + 10240);  // [128][40]
  unsigned int*   WHs = (unsigned int*)(smem + 20480);    // [64][20]
  unsigned int*   WLs = (unsigned int*)(smem + 25600);    // [64][20]
  const int c0    = bx * 64;
  const int kbase = by * kchunk;
  const int lane  = t & 63, wave = t >> 6;
  const int ml    = lane & 15, q = lane >> 4;
  const int r0    = wave * 32;
  const int ra = t >> 2, qa = t & 3;            // A staging: 64 rows x 4 chunks
  const int kp = t & 15, n4 = (t >> 4) * 4;     // W staging

  f32x4 acc[2][4];
  #pragma unroll
  for (int i = 0; i < 2; i++)
    #pragma unroll
    for (int j = 0; j < 4; j++) acc[i][j] = (f32x4){0.f, 0.f, 0.f, 0.f};

  const unsigned short* ahp = Ahi + (size_t)ra * K + kbase + qa * 8;
  const unsigned short* alp = Alo + (size_t)ra * K + kbase + qa * 8;
  const float*          wp  = W + (size_t)(kbase + 2 * kp) * N + c0 + n4;
  uint4  vah0 = *(const uint4*)ahp;
  uint4  vah1 = *(const uint4*)(ahp + (size_t)64 * K);
  uint4  val0 = *(const uint4*)alp;
  uint4  val1 = *(const uint4*)(alp + (size_t)64 * K);
  float4 vw0 = *(const float4*)wp;
  float4 vw1 = *(const float4*)(wp + N);

  const int nkt = kchunk >> 5;
  for (int kt = 0; kt < nkt; kt++) {
    *(uint4*)(AHs + ra * 40 + qa * 8)        = vah0;
    *(uint4*)(AHs + (ra + 64) * 40 + qa * 8) = vah1;
    *(uint4*)(ALs + ra * 40 + qa * 8)        = val0;
    *(uint4*)(ALs + (ra + 64) * 40 + qa * 8) = val1;
    {
      float w0[4], w1[4];
      *(float4*)w0 = vw0; *(float4*)w1 = vw1;
      #pragma unroll
      for (int c = 0; c < 4; c++) {
        unsigned int hu = pack_bf16_rne(w0[c], w1[c]);
        float f0 = bf2f((unsigned short)(hu & 0xFFFFu));
        float f1 = bf2f((unsigned short)(hu >> 16));
        unsigned int lu = pack_bf16_rne(w0[c] - f0, w1[c] - f1);
        WHs[(n4 + c) * 20 + kp] = hu;
        WLs[(n4 + c) * 20 + kp] = lu;
      }
    }
    __syncthreads();
    if (kt + 1 < nkt) {                          // prefetch next k-tile
      ahp += 32; alp += 32;
      wp  += (size_t)32 * N;
      vah0 = *(const uint4*)ahp;
      vah1 = *(const uint4*)(ahp + (size_t)64 * K);
      val0 = *(const uint4*)alp;
      val1 = *(const uint4*)(alp + (size_t)64 * K);
      vw0 = *(const float4*)wp;
      vw1 = *(const float4*)(wp + N);
    }
    bf16x8 ah0 = *(const bf16x8*)(AHs + (r0 + ml) * 40 + q * 8);
    bf16x8 ah1 = *(const bf16x8*)(AHs + (r0 + 16 + ml) * 40 + q * 8);
    bf16x8 al0 = *(const bf16x8*)(ALs + (r0 + ml) * 40 + q * 8);
    bf16x8 al1 = *(const bf16x8*)(ALs + (r0 + 16 + ml) * 40 + q * 8);
    #pragma unroll
    for (int ct = 0; ct < 4; ct++) {
      bf16x8 bh = *(const bf16x8*)((const unsigned short*)WHs +
                                   (size_t)((ct * 16 + ml) * 20 + q * 4) * 2);
      bf16x8 bl = *(const bf16x8*)((const unsigned short*)WLs +
                                   (size_t)((ct * 16 + ml) * 20 + q * 4) * 2);
      acc[0][ct] = __builtin_amdgcn_mfma_f32_16x16x32_bf16(ah0, bh, acc[0][ct], 0, 0, 0);
      acc[1][ct] = __builtin_amdgcn_mfma_f32_16x16x32_bf16(ah1, bh, acc[1][ct], 0, 0, 0);
      acc[0][ct] = __builtin_amdgcn_mfma_f32_16x16x32_bf16(ah0, bl, acc[0][ct], 0, 0, 0);
      acc[1][ct] = __builtin_amdgcn_mfma_f32_16x16x32_bf16(ah1, bl, acc[1][ct], 0, 0, 0);
      acc[0][ct] = __builtin_amdgcn_mfma_f32_16x16x32_bf16(al0, bh, acc[0][ct], 0, 0, 0);
      acc[1][ct] = __builtin_amdgcn_mfma_f32_16x16x32_bf16(al1, bh, acc[1][ct], 0, 0, 0);
    }
    __syncthreads();
  }

  // C/D layout: col = lane&15, row = (lane>>4)*4 + reg
  float* op = P + (size_t)by * 128 * N;
  #pragma unroll
  for (int rt = 0; rt < 2; rt++)
    #pragma unroll
    for (int ct = 0; ct < 4; ct++) {
      const int col = c0 + ct * 16 + ml;
      const int row = r0 + rt * 16 + q * 4;
      #pragma unroll
      for (int i = 0; i < 4; i++)
        op[(size_t)(row + i) * N + col] = acc[rt][ct][i];
    }
}

// ---------------------------------------------------------------------------
// Sum S partials + bias + LeakyReLU; optional fp32 out + bf16 hi/lo planes.
// One float4 per thread.
// ---------------------------------------------------------------------------
static __device__ __forceinline__ void reduce_body(
    const float* __restrict__ P, const float* __restrict__ bias,
    float* __restrict__ outF, unsigned short* __restrict__ outHi,
    unsigned short* __restrict__ outLo, int N, int S, int ldo, int gid)
{
  const int c4 = N >> 2;
  if (gid >= 128 * c4) return;
  const int r = gid / c4;
  const int c = (gid - r * c4) * 4;
  float4 s = make_float4(0, 0, 0, 0);
  for (int si = 0; si < S; si++) {
    float4 p = *(const float4*)(P + (size_t)si * 128 * N + (size_t)r * N + c);
    s.x += p.x; s.y += p.y; s.z += p.z; s.w += p.w;
  }
  float4 b = *(const float4*)(bias + c);
  s.x = lrelu(s.x + b.x); s.y = lrelu(s.y + b.y);
  s.z = lrelu(s.z + b.z); s.w = lrelu(s.w + b.w);
  if (outF) *(float4*)(outF + (size_t)r * ldo + c) = s;
  if (outHi) {
    ushort4 uh;
    uh.x = (unsigned short)f2bf(s.x); uh.y = (unsigned short)f2bf(s.y);
    uh.z = (unsigned short)f2bf(s.z); uh.w = (unsigned short)f2bf(s.w);
    *(ushort4*)(outHi + (size_t)r * N + c) = uh;
    if (outLo) {
      ushort4 ul;
      ul.x = (unsigned short)f2bf(s.x - bf2f(uh.x));
      ul.y = (unsigned short)f2bf(s.y - bf2f(uh.y));
      ul.z = (unsigned short)f2bf(s.z - bf2f(uh.z));
      ul.w = (unsigned short)f2bf(s.w - bf2f(uh.w));
      *(ushort4*)(outLo + (size_t)r * N + c) = ul;
    }
  }
}

// ---------------------------------------------------------------------------
// gemm4: M = h3(bf16) @ T(fp32->bf16), full K=1024, tile 128x64, 32 k-tiles.
// blocks 0..159. smem: 15360 B. Output accM bf16 [128][10240].
// ---------------------------------------------------------------------------
static __device__ __forceinline__ void gemm4_body(
    const unsigned short* __restrict__ h3b, const float* __restrict__ T,
    unsigned short* __restrict__ accM, int bx, int t, char* smem)
{
  unsigned short* Asm = (unsigned short*)smem;           // [128][40]
  unsigned int*   Wst = (unsigned int*)(smem + 10240);   // [64][20]
  const int c0   = bx * 64;
  const int lane = t & 63, wave = t >> 6;
  const int ml   = lane & 15, q = lane >> 4;
  const int r0   = wave * 32;
  const int ra = t >> 2, qa = t & 3;
  const int kp = t & 15, n4 = (t >> 4) * 4;

  f32x4 acc[2][4];
  #pragma unroll
  for (int i = 0; i < 2; i++)
    #pragma unroll
    for (int j = 0; j < 4; j++) acc[i][j] = (f32x4){0.f, 0.f, 0.f, 0.f};

  const unsigned short* ap = h3b + (size_t)ra * 1024 + qa * 8;
  const float*          tp = T + (size_t)(2 * kp) * 10240 + c0 + n4;
  uint4  va0 = *(const uint4*)ap;
  uint4  va1 = *(const uint4*)(ap + 64 * 1024);
  float4 vw0 = *(const float4*)tp;
  float4 vw1 = *(const float4*)(tp + 10240);

  for (int kt = 0; kt < 32; kt++) {
    *(uint4*)(Asm + ra * 40 + qa * 8)        = va0;
    *(uint4*)(Asm + (ra + 64) * 40 + qa * 8) = va1;
    Wst[(n4 + 0) * 20 + kp] = f2bf(vw0.x) | (f2bf(vw1.x) << 16);
    Wst[(n4 + 1) * 20 + kp] = f2bf(vw0.y) | (f2bf(vw1.y) << 16);
    Wst[(n4 + 2) * 20 + kp] = f2bf(vw0.z) | (f2bf(vw1.z) << 16);
    Wst[(n4 + 3) * 20 + kp] = f2bf(vw0.w) | (f2bf(vw1.w) << 16);
    __syncthreads();
    if (kt < 31) {                               // prefetch next k-tile
      ap += 32;
      tp += (size_t)32 * 10240;
      va0 = *(const uint4*)ap;
      va1 = *(const uint4*)(ap + 64 * 1024);
      vw0 = *(const float4*)tp;
      vw1 = *(const float4*)(tp + 10240);
    }
    bf16x8 a0 = *(const bf16x8*)(Asm + (r0 + ml) * 40 + q * 8);
    bf16x8 a1 = *(const bf16x8*)(Asm + (r0 + 16 + ml) * 40 + q * 8);
    #pragma unroll
    for (int ct = 0; ct < 4; ct++) {
      bf16x8 b = *(const bf16x8*)((const unsigned short*)Wst +
                                  (size_t)((ct * 16 + ml) * 20 + q * 4) * 2);
      acc[0][ct] = __builtin_amdgcn_mfma_f32_16x16x32_bf16(a0, b, acc[0][ct], 0, 0, 0);
      acc[1][ct] = __builtin_amdgcn_mfma_f32_16x16x32_bf16(a1, b, acc[1][ct], 0, 0, 0);
    }
    __syncthreads();
  }

  #pragma unroll
  for (int rt = 0; rt < 2; rt++)
    #pragma unroll
    for (int ct = 0; ct < 4; ct++) {
      int col = c0 + ct * 16 + ml;
      int row = r0 + rt * 16 + q * 4;
      #pragma unroll
      for (int i = 0; i < 4; i++)
        accM[(size_t)(row + i) * 10240 + col] = (unsigned short)f2bf(acc[rt][ct][i]);
    }
}

// ---------------------------------------------------------------------------
// pairwise for one o, 256 thr: o_b[j] = sum_i exp(-sum_k |M[i,o,k]-M[j,o,k]|)-1.
// smem: Ml f32[128][20] + parts f32[4][128] = 12288 B.
// ---------------------------------------------------------------------------
static __device__ __forceinline__ void pairwise_body(
    const unsigned short* __restrict__ accM, float* __restrict__ feat,
    int o, int t, char* smem)
{
  float* Ml    = (float*)smem;
  float* parts = (float*)(smem + 10240);
  {
    int i = t >> 1, kh = (t & 1) * 10;
    const unsigned short* p = accM + (size_t)i * 10240 + o * 20 + kh;
    #pragma unroll
    for (int k = 0; k < 10; k++) Ml[i * 20 + kh + k] = bf2f(p[k]);
  }
  __syncthreads();

  const int jg = t & 63, strip = t >> 6;   // 64 j-groups x 4 i-strips
  float mj[2][20];
  #pragma unroll
  for (int c = 0; c < 2; c++) {
    const float* src = Ml + (size_t)(jg * 2 + c) * 20;
    #pragma unroll
    for (int k = 0; k < 20; k++) mj[c][k] = src[k];
  }
  float acc2[2] = {0.f, 0.f};
  for (int ii = 0; ii < 32; ii++) {
    int i = strip * 32 + ii;
    const float4* m4 = (const float4*)(Ml + (size_t)i * 20);
    float mi[20];
    *(float4*)(mi + 0)  = m4[0]; *(float4*)(mi + 4)  = m4[1];
    *(float4*)(mi + 8)  = m4[2]; *(float4*)(mi + 12) = m4[3];
    *(float4*)(mi + 16) = m4[4];
    #pragma unroll
    for (int c = 0; c < 2; c++) {
      float norm = 0.f;
      #pragma unroll
      for (int k = 0; k < 20; k++) norm += fabsf(mi[k] - mj[c][k]);
      acc2[c] += __expf(-norm);
    }
  }
  parts[strip * 128 + jg * 2 + 0] = acc2[0];
  parts[strip * 128 + jg * 2 + 1] = acc2[1];
  __syncthreads();
  if (t < 128) {
    float s = parts[t] + parts[128 + t] + parts[256 + t] + parts[384 + t];
    feat[(size_t)t * 1536 + 1024 + o] = s - 1.0f;
  }
  __syncthreads();   // protect Ml/parts for next o
}

// ---------------------------------------------------------------------------
// final: out[r] = feat[r,:] . Wc + bc
// ---------------------------------------------------------------------------
static __device__ __forceinline__ void final_body(
    const float* __restrict__ feat, const float* __restrict__ Wc,
    const float* __restrict__ bc, float* __restrict__ out,
    int r, int t, char* smem)
{
  float* red = (float*)smem;
  float s = 0.f;
  for (int c = t; c < 1536; c += 256) s += feat[(size_t)r * 1536 + c] * Wc[c];
  for (int off = 32; off > 0; off >>= 1) s += __shfl_down(s, off);
  if ((t & 63) == 0) red[t >> 6] = s;
  __syncthreads();
  if (t == 0) out[r] = red[0] + red[1] + red[2] + red[3] + bc[0];
}

// ---------------------------------------------------------------------------
// Fused persistent kernel: all phases, grid 256 x 256, software grid barrier.
// ---------------------------------------------------------------------------
__global__ __launch_bounds__(256, 1) void fused_all(
    const float* __restrict__ X,
    const float* __restrict__ W1, const float* __restrict__ b1,
    const float* __restrict__ W2, const float* __restrict__ b2,
    const float* __restrict__ W3, const float* __restrict__ b3,
    const float* __restrict__ T,  const float* __restrict__ Wc,
    const float* __restrict__ bc, char* __restrict__ ws,
    float* __restrict__ out)
{
  __shared__ __align__(16) char smem[30720];
  const int b = blockIdx.x, t = threadIdx.x;
  const int g = b * 256 + t;
  float*          P    = (float*)ws;
  unsigned short* accM = (unsigned short*)ws;
  unsigned short* Xhi  = (unsigned short*)(ws + OFF_XHI);
  unsigned short* Xlo  = (unsigned short*)(ws + OFF_XLO);
  unsigned short* h1hi = (unsigned short*)(ws + OFF_H1HI);
  unsigned short* h1lo = (unsigned short*)(ws + OFF_H1LO);
  unsigned short* h2hi = (unsigned short*)(ws + OFF_H2HI);
  unsigned short* h2lo = (unsigned short*)(ws + OFF_H2LO);
  unsigned short* h3hi = (unsigned short*)(ws + OFF_H3HI);
  float*          feat = (float*)(ws + OFF_FEAT);

  convert_body(X, Xhi, Xlo, g);
  gbar(t);
  gemm3_body(Xhi, Xlo, W1, P, 2048, 2048, 256, b & 31, b >> 5, t, smem);
  gbar(t);
  reduce_body(P, b1, nullptr, h1hi, h1lo, 2048, 8, 0, g);
  gbar(t);
  gemm3_body(h1hi, h1lo, W2, P, 2048, 1024, 128, b & 15, b >> 4, t, smem);
  gbar(t);
  reduce_body(P, b2, nullptr, h2hi, h2lo, 1024, 16, 0, g);
  gbar(t);
  gemm3_body(h2hi, h2lo, W3, P, 1024, 1024, 64, b & 15, b >> 4, t, smem);
  gbar(t);
  reduce_body(P, b3, feat, h3hi, nullptr, 1024, 16, 1536, g);
  gbar(t);
  if (b < 160) gemm4_body(h3hi, T, accM, b, t, smem);
  gbar(t);
  pairwise_body(accM, feat, b * 2 + 0, t, smem);
  pairwise_body(accM, feat, b * 2 + 1, t, smem);
  gbar(t);
  if (b < 128) final_body(feat, Wc, bc, out, b, t, smem);
}

// ---------------------------------------------------------------------------
extern "C" void kernel_launch(void* const* d_in, const int* in_sizes, int n_in,
                              void* d_out, int out_size, void* d_ws, size_t ws_size,
                              hipStream_t stream)
{
  const float* X  = (const float*)d_in[0];
  const float* W1 = (const float*)d_in[1];
  const float* b1 = (const float*)d_in[2];
  const float* W2 = (const float*)d_in[3];
  const float* b2 = (const float*)d_in[4];
  const float* W3 = (const float*)d_in[5];
  const float* b3 = (const float*)d_in[6];
  const float* T  = (const float*)d_in[7];
  const float* Wc = (const float*)d_in[8];
  const float* bc = (const float*)d_in[9];
  char*  ws  = (char*)d_ws;
  float* out = (float*)d_out;

  fused_all<<<dim3(NBLK), dim3(256), 0, stream>>>(
      X, W1, b1, W2, b2, W3, b3, T, Wc, bc, ws, out);
}

// Round 5
// 664.657 us; speedup vs baseline: 1.2771x; 1.2771x over previous
//
#include <hip/hip_runtime.h>
#include <hip/hip_bf16.h>

// ---------------------------------------------------------------------------
// Fused persistent kernel v2. Grid 512 x 256 thr (2 blocks/CU guaranteed
// resident: 30.7KB LDS -> 5/CU capacity). Phases separated by an all-to-all
// FLAG barrier (per-block release-store to own slot -> parallel arrivals;
// block0/wave0 polls flags and publishes g_gen; everyone spins on g_gen).
// R4 lesson: a single atomic counter serializes 256 cross-XCD RMWs at ~700cy
// = 75us/barrier; distinct-address flags remove the serialization.
// Phases:
//  P1 g1: L1 gemm (X fp32 staged->hi/lo in LDS; 3-split MFMA; 32x8 tiles)
//  P2 r1 -> h1 planes          P3 g2 (16x16)        P4 r2 -> h2 planes
//  P5 g3 (16x8, kchunk 128)    P6 r3 -> feat[:, :1024] + h3hi
//  P7 g4: M = h3 @ T, split-2 (320 blocks) -> accM bf16 [2][128][10240]
//  P8 pairwise (1 o/block, 512 blocks) -> feat[:, 1024:]
//  P9 final_dot (128 blocks)
// ws layout (bytes):
//   [0, 8388608)         P fp32 partials (exactly 8MB worst) / accM (5.24MB)
//   [8388608, 8912896)   h1hi 128x2048 bf16
//   [8912896, 9437184)   h1lo
//   [9437184, 9699328)   h2hi 128x1024 bf16
//   [9699328, 9961472)   h2lo
//   [9961472, 10223616)  h3hi
//   [10223616, 11010048) feat 128x1536 f32
// ---------------------------------------------------------------------------

typedef __bf16 bf16x8 __attribute__((ext_vector_type(8)));
typedef __bf16 bf16x2 __attribute__((ext_vector_type(2)));
typedef float  f32x4  __attribute__((ext_vector_type(4)));

#define OFF_H1HI 8388608
#define OFF_H1LO 8912896
#define OFF_H2HI 9437184
#define OFF_H2LO 9699328
#define OFF_H3HI 9961472
#define OFF_FEAT 10223616

#define NBLK 512

// Barrier state: zero-init at module load; strictly monotonic (flags/gen only
// ever increase), so graph replays need no reset.
__device__ unsigned g_flag[NBLK];
__device__ unsigned g_gen;

static __device__ __forceinline__ void gbar(int b, int t, unsigned ph) {
  __syncthreads();                       // all waves of this block drained
  if (t == 0) {
    __threadfence();                     // release: writeback this XCD's L2
    __hip_atomic_store(&g_flag[b], ph, __ATOMIC_RELEASE, __HIP_MEMORY_SCOPE_AGENT);
  }
  if (b == 0 && t < 64) {                // wave 0 of block 0 collects arrivals
    unsigned ok = 0;
    for (unsigned it = 0; it < (1u << 20); ++it) {
      unsigned mn = 0xFFFFFFFFu;
      #pragma unroll
      for (int i = 0; i < NBLK / 64; i++) {
        unsigned v = __hip_atomic_load(&g_flag[t + i * 64], __ATOMIC_RELAXED,
                                       __HIP_MEMORY_SCOPE_AGENT);
        mn = v < mn ? v : mn;
      }
      if (__ballot(mn >= ph) == ~0ull) { ok = 1; break; }
      __builtin_amdgcn_s_sleep(1);
    }
    (void)ok;                            // timeout -> publish anyway (no wedge)
    if (t == 0)
      __hip_atomic_store(&g_gen, ph, __ATOMIC_RELEASE, __HIP_MEMORY_SCOPE_AGENT);
  }
  if (t == 0) {
    for (unsigned it = 0; it < (1u << 20); ++it) {
      if (__hip_atomic_load(&g_gen, __ATOMIC_ACQUIRE, __HIP_MEMORY_SCOPE_AGENT) >= ph)
        break;
      __builtin_amdgcn_s_sleep(1);
    }
    __threadfence();                     // acquire: invalidate stale L1/L2
  }
  __syncthreads();
}

static __device__ __forceinline__ unsigned int f2bf(float f) {
  union { float f; unsigned int u; } v; v.f = f;
  unsigned int r = v.u + 0x7FFFu + ((v.u >> 16) & 1u);   // RNE to bf16
  return r >> 16;
}
static __device__ __forceinline__ float bf2f(unsigned short u) {
  union { unsigned int u; float f; } v; v.u = ((unsigned int)u) << 16;
  return v.f;
}
static __device__ __forceinline__ unsigned int pack_bf16_rne(float a, float b) {
  bf16x2 v; v[0] = (__bf16)a; v[1] = (__bf16)b;
  return __builtin_bit_cast(unsigned int, v);
}
static __device__ __forceinline__ float lrelu(float x) {
  return x >= 0.0f ? x : 0.01f * x;
}
// 8 fp32 -> bf16 hi plane (uint4) + lo plane (uint4)
static __device__ __forceinline__ void split8(const float* x, uint4& h, uint4& l) {
  unsigned* hp = (unsigned*)&h; unsigned* lp = (unsigned*)&l;
  #pragma unroll
  for (int i = 0; i < 4; i++) {
    float x0 = x[2 * i], x1 = x[2 * i + 1];
    unsigned hu = pack_bf16_rne(x0, x1);
    float f0 = bf2f((unsigned short)(hu & 0xFFFFu));
    float f1 = bf2f((unsigned short)(hu >> 16));
    hp[i] = hu;
    lp[i] = pack_bf16_rne(x0 - f0, x1 - f1);
  }
}

// ---------------------------------------------------------------------------
// P1: L1 gemm with A = X fp32, split to hi/lo during LDS staging (convert
// kernel folded in). Tile 128x64, k-tile 32, kchunk 256 (8 k-tiles), K=N=2048.
// ---------------------------------------------------------------------------
static __device__ __forceinline__ void gemm1_body(
    const float* __restrict__ X, const float* __restrict__ W,
    float* __restrict__ P, int bx, int by, int t, char* smem)
{
  unsigned short* AHs = (unsigned short*)smem;            // [128][40]
  unsigned short* ALs = (unsigned short*)(smem + 10240);
  unsigned int*   WHs = (unsigned int*)(smem + 20480);    // [64][20]
  unsigned int*   WLs = (unsigned int*)(smem + 25600);
  const int c0    = bx * 64;
  const int kbase = by * 256;
  const int lane  = t & 63, wave = t >> 6;
  const int ml    = lane & 15, q = lane >> 4;
  const int r0    = wave * 32;
  const int ra = t >> 2, qa = t & 3;
  const int kp = t & 15, n4 = (t >> 4) * 4;

  f32x4 acc[2][4];
  #pragma unroll
  for (int i = 0; i < 2; i++)
    #pragma unroll
    for (int j = 0; j < 4; j++) acc[i][j] = (f32x4){0.f, 0.f, 0.f, 0.f};

  const float* xp0 = X + (size_t)ra * 2048 + kbase + qa * 8;
  const float* xp1 = xp0 + (size_t)64 * 2048;
  const float* wp  = W + (size_t)(kbase + 2 * kp) * 2048 + c0 + n4;
  float xr0[8], xr1[8];
  *(float4*)(xr0 + 0) = *(const float4*)xp0;
  *(float4*)(xr0 + 4) = *(const float4*)(xp0 + 4);
  *(float4*)(xr1 + 0) = *(const float4*)xp1;
  *(float4*)(xr1 + 4) = *(const float4*)(xp1 + 4);
  float4 vw0 = *(const float4*)wp;
  float4 vw1 = *(const float4*)(wp + 2048);

  for (int kt = 0; kt < 8; kt++) {
    uint4 h0, l0, h1, l1;
    split8(xr0, h0, l0); split8(xr1, h1, l1);
    *(uint4*)(AHs + ra * 40 + qa * 8)        = h0;
    *(uint4*)(AHs + (ra + 64) * 40 + qa * 8) = h1;
    *(uint4*)(ALs + ra * 40 + qa * 8)        = l0;
    *(uint4*)(ALs + (ra + 64) * 40 + qa * 8) = l1;
    {
      float w0[4], w1[4];
      *(float4*)w0 = vw0; *(float4*)w1 = vw1;
      #pragma unroll
      for (int c = 0; c < 4; c++) {
        unsigned int hu = pack_bf16_rne(w0[c], w1[c]);
        float f0 = bf2f((unsigned short)(hu & 0xFFFFu));
        float f1 = bf2f((unsigned short)(hu >> 16));
        unsigned int lu = pack_bf16_rne(w0[c] - f0, w1[c] - f1);
        WHs[(n4 + c) * 20 + kp] = hu;
        WLs[(n4 + c) * 20 + kp] = lu;
      }
    }
    __syncthreads();
    if (kt < 7) {
      xp0 += 32; xp1 += 32;
      wp  += (size_t)32 * 2048;
      *(float4*)(xr0 + 0) = *(const float4*)xp0;
      *(float4*)(xr0 + 4) = *(const float4*)(xp0 + 4);
      *(float4*)(xr1 + 0) = *(const float4*)xp1;
      *(float4*)(xr1 + 4) = *(const float4*)(xp1 + 4);
      vw0 = *(const float4*)wp;
      vw1 = *(const float4*)(wp + 2048);
    }
    bf16x8 ah0 = *(const bf16x8*)(AHs + (r0 + ml) * 40 + q * 8);
    bf16x8 ah1 = *(const bf16x8*)(AHs + (r0 + 16 + ml) * 40 + q * 8);
    bf16x8 al0 = *(const bf16x8*)(ALs + (r0 + ml) * 40 + q * 8);
    bf16x8 al1 = *(const bf16x8*)(ALs + (r0 + 16 + ml) * 40 + q * 8);
    #pragma unroll
    for (int ct = 0; ct < 4; ct++) {
      bf16x8 bh = *(const bf16x8*)((const unsigned short*)WHs +
                                   (size_t)((ct * 16 + ml) * 20 + q * 4) * 2);
      bf16x8 bl = *(const bf16x8*)((const unsigned short*)WLs +
                                   (size_t)((ct * 16 + ml) * 20 + q * 4) * 2);
      acc[0][ct] = __builtin_amdgcn_mfma_f32_16x16x32_bf16(ah0, bh, acc[0][ct], 0, 0, 0);
      acc[1][ct] = __builtin_amdgcn_mfma_f32_16x16x32_bf16(ah1, bh, acc[1][ct], 0, 0, 0);
      acc[0][ct] = __builtin_amdgcn_mfma_f32_16x16x32_bf16(ah0, bl, acc[0][ct], 0, 0, 0);
      acc[1][ct] = __builtin_amdgcn_mfma_f32_16x16x32_bf16(ah1, bl, acc[1][ct], 0, 0, 0);
      acc[0][ct] = __builtin_amdgcn_mfma_f32_16x16x32_bf16(al0, bh, acc[0][ct], 0, 0, 0);
      acc[1][ct] = __builtin_amdgcn_mfma_f32_16x16x32_bf16(al1, bh, acc[1][ct], 0, 0, 0);
    }
    __syncthreads();
  }

  float* op = P + (size_t)by * 128 * 2048;
  #pragma unroll
  for (int rt = 0; rt < 2; rt++)
    #pragma unroll
    for (int ct = 0; ct < 4; ct++) {
      const int col = c0 + ct * 16 + ml;
      const int row = r0 + rt * 16 + q * 4;
      #pragma unroll
      for (int i = 0; i < 4; i++)
        op[(size_t)(row + i) * 2048 + col] = acc[rt][ct][i];
    }
}

// ---------------------------------------------------------------------------
// Dense-layer GEMM on pre-split bf16 planes (layers 2,3); verified structure.
// ---------------------------------------------------------------------------
static __device__ __forceinline__ void gemm3_body(
    const unsigned short* __restrict__ Ahi, const unsigned short* __restrict__ Alo,
    const float* __restrict__ W, float* __restrict__ P,
    int K, int N, int kchunk, int bx, int by, int t, char* smem)
{
  unsigned short* AHs = (unsigned short*)smem;
  unsigned short* ALs = (unsigned short*)(smem + 10240);
  unsigned int*   WHs = (unsigned int*)(smem + 20480);
  unsigned int*   WLs = (unsigned int*)(smem + 25600);
  const int c0    = bx * 64;
  const int kbase = by * kchunk;
  const int lane  = t & 63, wave = t >> 6;
  const int ml    = lane & 15, q = lane >> 4;
  const int r0    = wave * 32;
  const int ra = t >> 2, qa = t & 3;
  const int kp = t & 15, n4 = (t >> 4) * 4;

  f32x4 acc[2][4];
  #pragma unroll
  for (int i = 0; i < 2; i++)
    #pragma unroll
    for (int j = 0; j < 4; j++) acc[i][j] = (f32x4){0.f, 0.f, 0.f, 0.f};

  const unsigned short* ahp = Ahi + (size_t)ra * K + kbase + qa * 8;
  const unsigned short* alp = Alo + (size_t)ra * K + kbase + qa * 8;
  const float*          wp  = W + (size_t)(kbase + 2 * kp) * N + c0 + n4;
  uint4  vah0 = *(const uint4*)ahp;
  uint4  vah1 = *(const uint4*)(ahp + (size_t)64 * K);
  uint4  val0 = *(const uint4*)alp;
  uint4  val1 = *(const uint4*)(alp + (size_t)64 * K);
  float4 vw0 = *(const float4*)wp;
  float4 vw1 = *(const float4*)(wp + N);

  const int nkt = kchunk >> 5;
  for (int kt = 0; kt < nkt; kt++) {
    *(uint4*)(AHs + ra * 40 + qa * 8)        = vah0;
    *(uint4*)(AHs + (ra + 64) * 40 + qa * 8) = vah1;
    *(uint4*)(ALs + ra * 40 + qa * 8)        = val0;
    *(uint4*)(ALs + (ra + 64) * 40 + qa * 8) = val1;
    {
      float w0[4], w1[4];
      *(float4*)w0 = vw0; *(float4*)w1 = vw1;
      #pragma unroll
      for (int c = 0; c < 4; c++) {
        unsigned int hu = pack_bf16_rne(w0[c], w1[c]);
        float f0 = bf2f((unsigned short)(hu & 0xFFFFu));
        float f1 = bf2f((unsigned short)(hu >> 16));
        unsigned int lu = pack_bf16_rne(w0[c] - f0, w1[c] - f1);
        WHs[(n4 + c) * 20 + kp] = hu;
        WLs[(n4 + c) * 20 + kp] = lu;
      }
    }
    __syncthreads();
    if (kt + 1 < nkt) {
      ahp += 32; alp += 32;
      wp  += (size_t)32 * N;
      vah0 = *(const uint4*)ahp;
      vah1 = *(const uint4*)(ahp + (size_t)64 * K);
      val0 = *(const uint4*)alp;
      val1 = *(const uint4*)(alp + (size_t)64 * K);
      vw0 = *(const float4*)wp;
      vw1 = *(const float4*)(wp + N);
    }
    bf16x8 ah0 = *(const bf16x8*)(AHs + (r0 + ml) * 40 + q * 8);
    bf16x8 ah1 = *(const bf16x8*)(AHs + (r0 + 16 + ml) * 40 + q * 8);
    bf16x8 al0 = *(const bf16x8*)(ALs + (r0 + ml) * 40 + q * 8);
    bf16x8 al1 = *(const bf16x8*)(ALs + (r0 + 16 + ml) * 40 + q * 8);
    #pragma unroll
    for (int ct = 0; ct < 4; ct++) {
      bf16x8 bh = *(const bf16x8*)((const unsigned short*)WHs +
                                   (size_t)((ct * 16 + ml) * 20 + q * 4) * 2);
      bf16x8 bl = *(const bf16x8*)((const unsigned short*)WLs +
                                   (size_t)((ct * 16 + ml) * 20 + q * 4) * 2);
      acc[0][ct] = __builtin_amdgcn_mfma_f32_16x16x32_bf16(ah0, bh, acc[0][ct], 0, 0, 0);
      acc[1][ct] = __builtin_amdgcn_mfma_f32_16x16x32_bf16(ah1, bh, acc[1][ct], 0, 0, 0);
      acc[0][ct] = __builtin_amdgcn_mfma_f32_16x16x32_bf16(ah0, bl, acc[0][ct], 0, 0, 0);
      acc[1][ct] = __builtin_amdgcn_mfma_f32_16x16x32_bf16(ah1, bl, acc[1][ct], 0, 0, 0);
      acc[0][ct] = __builtin_amdgcn_mfma_f32_16x16x32_bf16(al0, bh, acc[0][ct], 0, 0, 0);
      acc[1][ct] = __builtin_amdgcn_mfma_f32_16x16x32_bf16(al1, bh, acc[1][ct], 0, 0, 0);
    }
    __syncthreads();
  }

  float* op = P + (size_t)by * 128 * N;
  #pragma unroll
  for (int rt = 0; rt < 2; rt++)
    #pragma unroll
    for (int ct = 0; ct < 4; ct++) {
      const int col = c0 + ct * 16 + ml;
      const int row = r0 + rt * 16 + q * 4;
      #pragma unroll
      for (int i = 0; i < 4; i++)
        op[(size_t)(row + i) * N + col] = acc[rt][ct][i];
    }
}

// ---------------------------------------------------------------------------
// Sum S partials + bias + LeakyReLU; optional fp32 out + bf16 hi/lo planes.
// ---------------------------------------------------------------------------
static __device__ __forceinline__ void reduce_body(
    const float* __restrict__ P, const float* __restrict__ bias,
    float* __restrict__ outF, unsigned short* __restrict__ outHi,
    unsigned short* __restrict__ outLo, int N, int S, int ldo, int gid)
{
  const int c4 = N >> 2;
  if (gid >= 128 * c4) return;
  const int r = gid / c4;
  const int c = (gid - r * c4) * 4;
  float4 s = make_float4(0, 0, 0, 0);
  for (int si = 0; si < S; si++) {
    float4 p = *(const float4*)(P + (size_t)si * 128 * N + (size_t)r * N + c);
    s.x += p.x; s.y += p.y; s.z += p.z; s.w += p.w;
  }
  float4 b = *(const float4*)(bias + c);
  s.x = lrelu(s.x + b.x); s.y = lrelu(s.y + b.y);
  s.z = lrelu(s.z + b.z); s.w = lrelu(s.w + b.w);
  if (outF) *(float4*)(outF + (size_t)r * ldo + c) = s;
  if (outHi) {
    ushort4 uh;
    uh.x = (unsigned short)f2bf(s.x); uh.y = (unsigned short)f2bf(s.y);
    uh.z = (unsigned short)f2bf(s.z); uh.w = (unsigned short)f2bf(s.w);
    *(ushort4*)(outHi + (size_t)r * N + c) = uh;
    if (outLo) {
      ushort4 ul;
      ul.x = (unsigned short)f2bf(s.x - bf2f(uh.x));
      ul.y = (unsigned short)f2bf(s.y - bf2f(uh.y));
      ul.z = (unsigned short)f2bf(s.z - bf2f(uh.z));
      ul.w = (unsigned short)f2bf(s.w - bf2f(uh.w));
      *(ushort4*)(outLo + (size_t)r * N + c) = ul;
    }
  }
}

// ---------------------------------------------------------------------------
// P7: M = h3(bf16) @ T(fp32->bf16), split-2 over K (kbase = ks*512, 16 kt).
// Tile 128x64; 320 blocks. Output accM bf16 [2][128][10240].
// ---------------------------------------------------------------------------
static __device__ __forceinline__ void gemm4_body(
    const unsigned short* __restrict__ h3b, const float* __restrict__ T,
    unsigned short* __restrict__ accM, int bx, int ks, int t, char* smem)
{
  unsigned short* Asm = (unsigned short*)smem;           // [128][40]
  unsigned int*   Wst = (unsigned int*)(smem + 10240);   // [64][20]
  const int c0   = bx * 64;
  const int kbase = ks * 512;
  const int lane = t & 63, wave = t >> 6;
  const int ml   = lane & 15, q = lane >> 4;
  const int r0   = wave * 32;
  const int ra = t >> 2, qa = t & 3;
  const int kp = t & 15, n4 = (t >> 4) * 4;

  f32x4 acc[2][4];
  #pragma unroll
  for (int i = 0; i < 2; i++)
    #pragma unroll
    for (int j = 0; j < 4; j++) acc[i][j] = (f32x4){0.f, 0.f, 0.f, 0.f};

  const unsigned short* ap = h3b + (size_t)ra * 1024 + kbase + qa * 8;
  const float*          tp = T + (size_t)(kbase + 2 * kp) * 10240 + c0 + n4;
  uint4  va0 = *(const uint4*)ap;
  uint4  va1 = *(const uint4*)(ap + 64 * 1024);
  float4 vw0 = *(const float4*)tp;
  float4 vw1 = *(const float4*)(tp + 10240);

  for (int kt = 0; kt < 16; kt++) {
    *(uint4*)(Asm + ra * 40 + qa * 8)        = va0;
    *(uint4*)(Asm + (ra + 64) * 40 + qa * 8) = va1;
    Wst[(n4 + 0) * 20 + kp] = f2bf(vw0.x) | (f2bf(vw1.x) << 16);
    Wst[(n4 + 1) * 20 + kp] = f2bf(vw0.y) | (f2bf(vw1.y) << 16);
    Wst[(n4 + 2) * 20 + kp] = f2bf(vw0.z) | (f2bf(vw1.z) << 16);
    Wst[(n4 + 3) * 20 + kp] = f2bf(vw0.w) | (f2bf(vw1.w) << 16);
    __syncthreads();
    if (kt < 15) {
      ap += 32;
      tp += (size_t)32 * 10240;
      va0 = *(const uint4*)ap;
      va1 = *(const uint4*)(ap + 64 * 1024);
      vw0 = *(const float4*)tp;
      vw1 = *(const float4*)(tp + 10240);
    }
    bf16x8 a0 = *(const bf16x8*)(Asm + (r0 + ml) * 40 + q * 8);
    bf16x8 a1 = *(const bf16x8*)(Asm + (r0 + 16 + ml) * 40 + q * 8);
    #pragma unroll
    for (int ct = 0; ct < 4; ct++) {
      bf16x8 b = *(const bf16x8*)((const unsigned short*)Wst +
                                  (size_t)((ct * 16 + ml) * 20 + q * 4) * 2);
      acc[0][ct] = __builtin_amdgcn_mfma_f32_16x16x32_bf16(a0, b, acc[0][ct], 0, 0, 0);
      acc[1][ct] = __builtin_amdgcn_mfma_f32_16x16x32_bf16(a1, b, acc[1][ct], 0, 0, 0);
    }
    __syncthreads();
  }

  unsigned short* outp = accM + (size_t)ks * 1310720;
  #pragma unroll
  for (int rt = 0; rt < 2; rt++)
    #pragma unroll
    for (int ct = 0; ct < 4; ct++) {
      int col = c0 + ct * 16 + ml;
      int row = r0 + rt * 16 + q * 4;
      #pragma unroll
      for (int i = 0; i < 4; i++)
        outp[(size_t)(row + i) * 10240 + col] = (unsigned short)f2bf(acc[rt][ct][i]);
    }
}

// ---------------------------------------------------------------------------
// P8: pairwise for one o, 256 thr; combines 2 K-splits of accM.
// smem: Ml f32[128][20] (10240B) + parts f32[4][128] (2048B).
// ---------------------------------------------------------------------------
static __device__ __forceinline__ void pairwise_body(
    const unsigned short* __restrict__ accM, float* __restrict__ feat,
    int o, int t, char* smem)
{
  float* Ml    = (float*)smem;
  float* parts = (float*)(smem + 10240);
  {
    int i = t >> 1, kh = (t & 1) * 10;
    const unsigned short* p = accM + (size_t)i * 10240 + o * 20 + kh;
    #pragma unroll
    for (int k = 0; k < 10; k++)
      Ml[i * 20 + kh + k] = bf2f(p[k]) + bf2f(p[1310720 + k]);
  }
  __syncthreads();

  const int jg = t & 63, strip = t >> 6;   // 64 j-groups x 4 i-strips
  float mj[2][20];
  #pragma unroll
  for (int c = 0; c < 2; c++) {
    const float* src = Ml + (size_t)(jg * 2 + c) * 20;
    #pragma unroll
    for (int k = 0; k < 20; k++) mj[c][k] = src[k];
  }
  float acc2[2] = {0.f, 0.f};
  for (int ii = 0; ii < 32; ii++) {
    int i = strip * 32 + ii;
    const float4* m4 = (const float4*)(Ml + (size_t)i * 20);
    float mi[20];
    *(float4*)(mi + 0)  = m4[0]; *(float4*)(mi + 4)  = m4[1];
    *(float4*)(mi + 8)  = m4[2]; *(float4*)(mi + 12) = m4[3];
    *(float4*)(mi + 16) = m4[4];
    #pragma unroll
    for (int c = 0; c < 2; c++) {
      float norm = 0.f;
      #pragma unroll
      for (int k = 0; k < 20; k++) norm += fabsf(mi[k] - mj[c][k]);
      acc2[c] += __expf(-norm);
    }
  }
  parts[strip * 128 + jg * 2 + 0] = acc2[0];
  parts[strip * 128 + jg * 2 + 1] = acc2[1];
  __syncthreads();
  if (t < 128) {
    float s = parts[t] + parts[128 + t] + parts[256 + t] + parts[384 + t];
    feat[(size_t)t * 1536 + 1024 + o] = s - 1.0f;
  }
  __syncthreads();
}

// ---------------------------------------------------------------------------
// P9: out[r] = feat[r,:] . Wc + bc
// ---------------------------------------------------------------------------
static __device__ __forceinline__ void final_body(
    const float* __restrict__ feat, const float* __restrict__ Wc,
    const float* __restrict__ bc, float* __restrict__ out,
    int r, int t, char* smem)
{
  float* red = (float*)smem;
  float s = 0.f;
  for (int c = t; c < 1536; c += 256) s += feat[(size_t)r * 1536 + c] * Wc[c];
  for (int off = 32; off > 0; off >>= 1) s += __shfl_down(s, off);
  if ((t & 63) == 0) red[t >> 6] = s;
  __syncthreads();
  if (t == 0) out[r] = red[0] + red[1] + red[2] + red[3] + bc[0];
}

// ---------------------------------------------------------------------------
__global__ __launch_bounds__(256, 2) void fused_all(
    const float* __restrict__ X,
    const float* __restrict__ W1, const float* __restrict__ b1,
    const float* __restrict__ W2, const float* __restrict__ b2,
    const float* __restrict__ W3, const float* __restrict__ b3,
    const float* __restrict__ T,  const float* __restrict__ Wc,
    const float* __restrict__ bc, char* __restrict__ ws,
    float* __restrict__ out)
{
  __shared__ __align__(16) char smem[30720];
  __shared__ unsigned sh_base;
  const int b = blockIdx.x, t = threadIdx.x;
  const int g = b * 256 + t;
  float*          P    = (float*)ws;
  unsigned short* accM = (unsigned short*)ws;
  unsigned short* h1hi = (unsigned short*)(ws + OFF_H1HI);
  unsigned short* h1lo = (unsigned short*)(ws + OFF_H1LO);
  unsigned short* h2hi = (unsigned short*)(ws + OFF_H2HI);
  unsigned short* h2lo = (unsigned short*)(ws + OFF_H2LO);
  unsigned short* h3hi = (unsigned short*)(ws + OFF_H3HI);
  float*          feat = (float*)(ws + OFF_FEAT);

  if (t == 0)
    sh_base = __hip_atomic_load(&g_gen, __ATOMIC_RELAXED, __HIP_MEMORY_SCOPE_AGENT);
  __syncthreads();
  const unsigned base = sh_base;

  if (b < 256) gemm1_body(X, W1, P, b & 31, b >> 5, t, smem);
  gbar(b, t, base + 1);
  reduce_body(P, b1, nullptr, h1hi, h1lo, 2048, 8, 0, g);
  gbar(b, t, base + 2);
  if (b < 256) gemm3_body(h1hi, h1lo, W2, P, 2048, 1024, 128, b & 15, b >> 4, t, smem);
  gbar(b, t, base + 3);
  reduce_body(P, b2, nullptr, h2hi, h2lo, 1024, 16, 0, g);
  gbar(b, t, base + 4);
  if (b < 128) gemm3_body(h2hi, h2lo, W3, P, 1024, 1024, 128, b & 15, b >> 4, t, smem);
  gbar(b, t, base + 5);
  reduce_body(P, b3, feat, h3hi, nullptr, 1024, 8, 1536, g);
  gbar(b, t, base + 6);
  if (b < 320) gemm4_body(h3hi, T, accM, b % 160, b / 160, t, smem);
  gbar(b, t, base + 7);
  pairwise_body(accM, feat, b, t, smem);
  gbar(b, t, base + 8);
  if (b < 128) final_body(feat, Wc, bc, out, b, t, smem);
}

// ---------------------------------------------------------------------------
extern "C" void kernel_launch(void* const* d_in, const int* in_sizes, int n_in,
                              void* d_out, int out_size, void* d_ws, size_t ws_size,
                              hipStream_t stream)
{
  const float* X  = (const float*)d_in[0];
  const float* W1 = (const float*)d_in[1];
  const float* b1 = (const float*)d_in[2];
  const float* W2 = (const float*)d_in[3];
  const float* b2 = (const float*)d_in[4];
  const float* W3 = (const float*)d_in[5];
  const float* b3 = (const float*)d_in[6];
  const float* T  = (const float*)d_in[7];
  const float* Wc = (const float*)d_in[8];
  const float* bc = (const float*)d_in[9];
  char*  ws  = (char*)d_ws;
  float* out = (float*)d_out;

  fused_all<<<dim3(NBLK), dim3(256), 0, stream>>>(
      X, W1, b1, W2, b2, W3, b3, T, Wc, bc, ws, out);
}

// Round 6
// 190.692 us; speedup vs baseline: 4.4514x; 3.4855x over previous
//
#include <hip/hip_runtime.h>
#include <hip/hip_bf16.h>

// ---------------------------------------------------------------------------
// Multi-kernel pipeline (persistent-kernel fusion abandoned: measured grid
// barrier cost ~60-78us on MI355X regardless of arrival pattern; HW kernel
// boundaries are ~6x cheaper).
//  k_gemm1   : L1 = lrelu(X@W1+b1) gemm, X fp32 split->hi/lo in LDS staging
//              (convert kernel folded in), 3-split MFMA, split-K 8 -> P
//  k_reduce  : partial-sum + bias + lrelu -> bf16 hi/lo planes (+fp32 feat)
//  k_gemm3 x2: L2/L3 gemms on pre-split bf16 planes, split-K -> P
//  k_gemm4   : M = h3 @ T, FULL K=1024 -> accM bf16 [128][10240] (2.6MB)
//  k_pairwise: o_b[j] = sum_i exp(-L1(M_i-M_j)) - 1 -> feat[:,1024:]
//  k_final   : out = feat @ Wc + bc
// All bodies harness-verified in prior rounds (R2/R4/R5), absmax 1.22e-4.
// ws layout (bytes):
//   [0, 8388608)         P fp32 partials (<=8MB) / accM bf16 (2.6MB)
//   [8388608, 8912896)   h1hi 128x2048 bf16
//   [8912896, 9437184)   h1lo
//   [9437184, 9699328)   h2hi 128x1024 bf16
//   [9699328, 9961472)   h2lo
//   [9961472, 10223616)  h3hi
//   [10223616, 11010048) feat 128x1536 f32
// ---------------------------------------------------------------------------

typedef __bf16 bf16x8 __attribute__((ext_vector_type(8)));
typedef __bf16 bf16x2 __attribute__((ext_vector_type(2)));
typedef float  f32x4  __attribute__((ext_vector_type(4)));

#define OFF_H1HI 8388608
#define OFF_H1LO 8912896
#define OFF_H2HI 9437184
#define OFF_H2LO 9699328
#define OFF_H3HI 9961472
#define OFF_FEAT 10223616

static __device__ __forceinline__ unsigned int f2bf(float f) {
  union { float f; unsigned int u; } v; v.f = f;
  unsigned int r = v.u + 0x7FFFu + ((v.u >> 16) & 1u);   // RNE to bf16
  return r >> 16;
}
static __device__ __forceinline__ float bf2f(unsigned short u) {
  union { unsigned int u; float f; } v; v.u = ((unsigned int)u) << 16;
  return v.f;
}
static __device__ __forceinline__ unsigned int pack_bf16_rne(float a, float b) {
  bf16x2 v; v[0] = (__bf16)a; v[1] = (__bf16)b;
  return __builtin_bit_cast(unsigned int, v);
}
static __device__ __forceinline__ float lrelu(float x) {
  return x >= 0.0f ? x : 0.01f * x;
}
// 8 fp32 -> bf16 hi plane (uint4) + lo plane (uint4)
static __device__ __forceinline__ void split8(const float* x, uint4& h, uint4& l) {
  unsigned* hp = (unsigned*)&h; unsigned* lp = (unsigned*)&l;
  #pragma unroll
  for (int i = 0; i < 4; i++) {
    float x0 = x[2 * i], x1 = x[2 * i + 1];
    unsigned hu = pack_bf16_rne(x0, x1);
    float f0 = bf2f((unsigned short)(hu & 0xFFFFu));
    float f1 = bf2f((unsigned short)(hu >> 16));
    hp[i] = hu;
    lp[i] = pack_bf16_rne(x0 - f0, x1 - f1);
  }
}

// ---------------------------------------------------------------------------
// L1 gemm: A = X fp32, split hi/lo during LDS staging. Tile 128x64, k-tile 32,
// kchunk 256 (8 k-tiles). Grid (32, 8). [R5-verified body]
// ---------------------------------------------------------------------------
__global__ __launch_bounds__(256, 2) void k_gemm1(
    const float* __restrict__ X, const float* __restrict__ W,
    float* __restrict__ P)
{
  __shared__ __align__(16) char smem[30720];
  unsigned short* AHs = (unsigned short*)smem;            // [128][40]
  unsigned short* ALs = (unsigned short*)(smem + 10240);
  unsigned int*   WHs = (unsigned int*)(smem + 20480);    // [64][20]
  unsigned int*   WLs = (unsigned int*)(smem + 25600);
  const int t     = threadIdx.x;
  const int c0    = blockIdx.x * 64;
  const int kbase = blockIdx.y * 256;
  const int lane  = t & 63, wave = t >> 6;
  const int ml    = lane & 15, q = lane >> 4;
  const int r0    = wave * 32;
  const int ra = t >> 2, qa = t & 3;
  const int kp = t & 15, n4 = (t >> 4) * 4;

  f32x4 acc[2][4];
  #pragma unroll
  for (int i = 0; i < 2; i++)
    #pragma unroll
    for (int j = 0; j < 4; j++) acc[i][j] = (f32x4){0.f, 0.f, 0.f, 0.f};

  const float* xp0 = X + (size_t)ra * 2048 + kbase + qa * 8;
  const float* xp1 = xp0 + (size_t)64 * 2048;
  const float* wp  = W + (size_t)(kbase + 2 * kp) * 2048 + c0 + n4;
  float xr0[8], xr1[8];
  *(float4*)(xr0 + 0) = *(const float4*)xp0;
  *(float4*)(xr0 + 4) = *(const float4*)(xp0 + 4);
  *(float4*)(xr1 + 0) = *(const float4*)xp1;
  *(float4*)(xr1 + 4) = *(const float4*)(xp1 + 4);
  float4 vw0 = *(const float4*)wp;
  float4 vw1 = *(const float4*)(wp + 2048);

  for (int kt = 0; kt < 8; kt++) {
    uint4 h0, l0, h1, l1;
    split8(xr0, h0, l0); split8(xr1, h1, l1);
    *(uint4*)(AHs + ra * 40 + qa * 8)        = h0;
    *(uint4*)(AHs + (ra + 64) * 40 + qa * 8) = h1;
    *(uint4*)(ALs + ra * 40 + qa * 8)        = l0;
    *(uint4*)(ALs + (ra + 64) * 40 + qa * 8) = l1;
    {
      float w0[4], w1[4];
      *(float4*)w0 = vw0; *(float4*)w1 = vw1;
      #pragma unroll
      for (int c = 0; c < 4; c++) {
        unsigned int hu = pack_bf16_rne(w0[c], w1[c]);
        float f0 = bf2f((unsigned short)(hu & 0xFFFFu));
        float f1 = bf2f((unsigned short)(hu >> 16));
        unsigned int lu = pack_bf16_rne(w0[c] - f0, w1[c] - f1);
        WHs[(n4 + c) * 20 + kp] = hu;
        WLs[(n4 + c) * 20 + kp] = lu;
      }
    }
    __syncthreads();
    if (kt < 7) {
      xp0 += 32; xp1 += 32;
      wp  += (size_t)32 * 2048;
      *(float4*)(xr0 + 0) = *(const float4*)xp0;
      *(float4*)(xr0 + 4) = *(const float4*)(xp0 + 4);
      *(float4*)(xr1 + 0) = *(const float4*)xp1;
      *(float4*)(xr1 + 4) = *(const float4*)(xp1 + 4);
      vw0 = *(const float4*)wp;
      vw1 = *(const float4*)(wp + 2048);
    }
    bf16x8 ah0 = *(const bf16x8*)(AHs + (r0 + ml) * 40 + q * 8);
    bf16x8 ah1 = *(const bf16x8*)(AHs + (r0 + 16 + ml) * 40 + q * 8);
    bf16x8 al0 = *(const bf16x8*)(ALs + (r0 + ml) * 40 + q * 8);
    bf16x8 al1 = *(const bf16x8*)(ALs + (r0 + 16 + ml) * 40 + q * 8);
    #pragma unroll
    for (int ct = 0; ct < 4; ct++) {
      bf16x8 bh = *(const bf16x8*)((const unsigned short*)WHs +
                                   (size_t)((ct * 16 + ml) * 20 + q * 4) * 2);
      bf16x8 bl = *(const bf16x8*)((const unsigned short*)WLs +
                                   (size_t)((ct * 16 + ml) * 20 + q * 4) * 2);
      acc[0][ct] = __builtin_amdgcn_mfma_f32_16x16x32_bf16(ah0, bh, acc[0][ct], 0, 0, 0);
      acc[1][ct] = __builtin_amdgcn_mfma_f32_16x16x32_bf16(ah1, bh, acc[1][ct], 0, 0, 0);
      acc[0][ct] = __builtin_amdgcn_mfma_f32_16x16x32_bf16(ah0, bl, acc[0][ct], 0, 0, 0);
      acc[1][ct] = __builtin_amdgcn_mfma_f32_16x16x32_bf16(ah1, bl, acc[1][ct], 0, 0, 0);
      acc[0][ct] = __builtin_amdgcn_mfma_f32_16x16x32_bf16(al0, bh, acc[0][ct], 0, 0, 0);
      acc[1][ct] = __builtin_amdgcn_mfma_f32_16x16x32_bf16(al1, bh, acc[1][ct], 0, 0, 0);
    }
    __syncthreads();
  }

  float* op = P + (size_t)blockIdx.y * 128 * 2048;
  #pragma unroll
  for (int rt = 0; rt < 2; rt++)
    #pragma unroll
    for (int ct = 0; ct < 4; ct++) {
      const int col = c0 + ct * 16 + ml;
      const int row = r0 + rt * 16 + q * 4;
      #pragma unroll
      for (int i = 0; i < 4; i++)
        op[(size_t)(row + i) * 2048 + col] = acc[rt][ct][i];
    }
}

// ---------------------------------------------------------------------------
// L2/L3 gemm on pre-split bf16 planes. Tile 128x64, k-tile 32, split-K.
// Grid (N/64, S). [R2-verified body]
// ---------------------------------------------------------------------------
__global__ __launch_bounds__(256, 2) void k_gemm3(
    const unsigned short* __restrict__ Ahi, const unsigned short* __restrict__ Alo,
    const float* __restrict__ W, float* __restrict__ P,
    int K, int N, int kchunk)
{
  __shared__ __align__(16) char smem[30720];
  unsigned short* AHs = (unsigned short*)smem;
  unsigned short* ALs = (unsigned short*)(smem + 10240);
  unsigned int*   WHs = (unsigned int*)(smem + 20480);
  unsigned int*   WLs = (unsigned int*)(smem + 25600);
  const int t     = threadIdx.x;
  const int c0    = blockIdx.x * 64;
  const int kbase = blockIdx.y * kchunk;
  const int lane  = t & 63, wave = t >> 6;
  const int ml    = lane & 15, q = lane >> 4;
  const int r0    = wave * 32;
  const int ra = t >> 2, qa = t & 3;
  const int kp = t & 15, n4 = (t >> 4) * 4;

  f32x4 acc[2][4];
  #pragma unroll
  for (int i = 0; i < 2; i++)
    #pragma unroll
    for (int j = 0; j < 4; j++) acc[i][j] = (f32x4){0.f, 0.f, 0.f, 0.f};

  const unsigned short* ahp = Ahi + (size_t)ra * K + kbase + qa * 8;
  const unsigned short* alp = Alo + (size_t)ra * K + kbase + qa * 8;
  const float*          wp  = W + (size_t)(kbase + 2 * kp) * N + c0 + n4;
  uint4  vah0 = *(const uint4*)ahp;
  uint4  vah1 = *(const uint4*)(ahp + (size_t)64 * K);
  uint4  val0 = *(const uint4*)alp;
  uint4  val1 = *(const uint4*)(alp + (size_t)64 * K);
  float4 vw0 = *(const float4*)wp;
  float4 vw1 = *(const float4*)(wp + N);

  const int nkt = kchunk >> 5;
  for (int kt = 0; kt < nkt; kt++) {
    *(uint4*)(AHs + ra * 40 + qa * 8)        = vah0;
    *(uint4*)(AHs + (ra + 64) * 40 + qa * 8) = vah1;
    *(uint4*)(ALs + ra * 40 + qa * 8)        = val0;
    *(uint4*)(ALs + (ra + 64) * 40 + qa * 8) = val1;
    {
      float w0[4], w1[4];
      *(float4*)w0 = vw0; *(float4*)w1 = vw1;
      #pragma unroll
      for (int c = 0; c < 4; c++) {
        unsigned int hu = pack_bf16_rne(w0[c], w1[c]);
        float f0 = bf2f((unsigned short)(hu & 0xFFFFu));
        float f1 = bf2f((unsigned short)(hu >> 16));
        unsigned int lu = pack_bf16_rne(w0[c] - f0, w1[c] - f1);
        WHs[(n4 + c) * 20 + kp] = hu;
        WLs[(n4 + c) * 20 + kp] = lu;
      }
    }
    __syncthreads();
    if (kt + 1 < nkt) {
      ahp += 32; alp += 32;
      wp  += (size_t)32 * N;
      vah0 = *(const uint4*)ahp;
      vah1 = *(const uint4*)(ahp + (size_t)64 * K);
      val0 = *(const uint4*)alp;
      val1 = *(const uint4*)(alp + (size_t)64 * K);
      vw0 = *(const float4*)wp;
      vw1 = *(const float4*)(wp + N);
    }
    bf16x8 ah0 = *(const bf16x8*)(AHs + (r0 + ml) * 40 + q * 8);
    bf16x8 ah1 = *(const bf16x8*)(AHs + (r0 + 16 + ml) * 40 + q * 8);
    bf16x8 al0 = *(const bf16x8*)(ALs + (r0 + ml) * 40 + q * 8);
    bf16x8 al1 = *(const bf16x8*)(ALs + (r0 + 16 + ml) * 40 + q * 8);
    #pragma unroll
    for (int ct = 0; ct < 4; ct++) {
      bf16x8 bh = *(const bf16x8*)((const unsigned short*)WHs +
                                   (size_t)((ct * 16 + ml) * 20 + q * 4) * 2);
      bf16x8 bl = *(const bf16x8*)((const unsigned short*)WLs +
                                   (size_t)((ct * 16 + ml) * 20 + q * 4) * 2);
      acc[0][ct] = __builtin_amdgcn_mfma_f32_16x16x32_bf16(ah0, bh, acc[0][ct], 0, 0, 0);
      acc[1][ct] = __builtin_amdgcn_mfma_f32_16x16x32_bf16(ah1, bh, acc[1][ct], 0, 0, 0);
      acc[0][ct] = __builtin_amdgcn_mfma_f32_16x16x32_bf16(ah0, bl, acc[0][ct], 0, 0, 0);
      acc[1][ct] = __builtin_amdgcn_mfma_f32_16x16x32_bf16(ah1, bl, acc[1][ct], 0, 0, 0);
      acc[0][ct] = __builtin_amdgcn_mfma_f32_16x16x32_bf16(al0, bh, acc[0][ct], 0, 0, 0);
      acc[1][ct] = __builtin_amdgcn_mfma_f32_16x16x32_bf16(al1, bh, acc[1][ct], 0, 0, 0);
    }
    __syncthreads();
  }

  float* op = P + (size_t)blockIdx.y * 128 * N;
  #pragma unroll
  for (int rt = 0; rt < 2; rt++)
    #pragma unroll
    for (int ct = 0; ct < 4; ct++) {
      const int col = c0 + ct * 16 + ml;
      const int row = r0 + rt * 16 + q * 4;
      #pragma unroll
      for (int i = 0; i < 4; i++)
        op[(size_t)(row + i) * N + col] = acc[rt][ct][i];
    }
}

// ---------------------------------------------------------------------------
// Sum S partials + bias + LeakyReLU; optional fp32 out + bf16 hi/lo planes.
// 256 thr, one float4 per thread. [R4-verified body]
// ---------------------------------------------------------------------------
__global__ __launch_bounds__(256) void k_reduce(
    const float* __restrict__ P, const float* __restrict__ bias,
    float* __restrict__ outF, unsigned short* __restrict__ outHi,
    unsigned short* __restrict__ outLo, int N, int S, int ldo)
{
  const int gid = blockIdx.x * 256 + threadIdx.x;
  const int c4 = N >> 2;
  if (gid >= 128 * c4) return;
  const int r = gid / c4;
  const int c = (gid - r * c4) * 4;
  float4 s = make_float4(0, 0, 0, 0);
  for (int si = 0; si < S; si++) {
    float4 p = *(const float4*)(P + (size_t)si * 128 * N + (size_t)r * N + c);
    s.x += p.x; s.y += p.y; s.z += p.z; s.w += p.w;
  }
  float4 b = *(const float4*)(bias + c);
  s.x = lrelu(s.x + b.x); s.y = lrelu(s.y + b.y);
  s.z = lrelu(s.z + b.z); s.w = lrelu(s.w + b.w);
  if (outF) *(float4*)(outF + (size_t)r * ldo + c) = s;
  if (outHi) {
    ushort4 uh;
    uh.x = (unsigned short)f2bf(s.x); uh.y = (unsigned short)f2bf(s.y);
    uh.z = (unsigned short)f2bf(s.z); uh.w = (unsigned short)f2bf(s.w);
    *(ushort4*)(outHi + (size_t)r * N + c) = uh;
    if (outLo) {
      ushort4 ul;
      ul.x = (unsigned short)f2bf(s.x - bf2f(uh.x));
      ul.y = (unsigned short)f2bf(s.y - bf2f(uh.y));
      ul.z = (unsigned short)f2bf(s.z - bf2f(uh.z));
      ul.w = (unsigned short)f2bf(s.w - bf2f(uh.w));
      *(ushort4*)(outLo + (size_t)r * N + c) = ul;
    }
  }
}

// ---------------------------------------------------------------------------
// gemm4: M = h3(bf16) @ T(fp32->bf16), FULL K=1024, tile 128x64, 32 k-tiles.
// Grid 160. Output accM bf16 [128][10240]. [R4-verified body]
// ---------------------------------------------------------------------------
__global__ __launch_bounds__(256, 2) void k_gemm4(
    const unsigned short* __restrict__ h3b, const float* __restrict__ T,
    unsigned short* __restrict__ accM)
{
  __shared__ __align__(16) char smem[15360];
  unsigned short* Asm = (unsigned short*)smem;           // [128][40]
  unsigned int*   Wst = (unsigned int*)(smem + 10240);   // [64][20]
  const int t    = threadIdx.x;
  const int c0   = blockIdx.x * 64;
  const int lane = t & 63, wave = t >> 6;
  const int ml   = lane & 15, q = lane >> 4;
  const int r0   = wave * 32;
  const int ra = t >> 2, qa = t & 3;
  const int kp = t & 15, n4 = (t >> 4) * 4;

  f32x4 acc[2][4];
  #pragma unroll
  for (int i = 0; i < 2; i++)
    #pragma unroll
    for (int j = 0; j < 4; j++) acc[i][j] = (f32x4){0.f, 0.f, 0.f, 0.f};

  const unsigned short* ap = h3b + (size_t)ra * 1024 + qa * 8;
  const float*          tp = T + (size_t)(2 * kp) * 10240 + c0 + n4;
  uint4  va0 = *(const uint4*)ap;
  uint4  va1 = *(const uint4*)(ap + 64 * 1024);
  float4 vw0 = *(const float4*)tp;
  float4 vw1 = *(const float4*)(tp + 10240);

  for (int kt = 0; kt < 32; kt++) {
    *(uint4*)(Asm + ra * 40 + qa * 8)        = va0;
    *(uint4*)(Asm + (ra + 64) * 40 + qa * 8) = va1;
    Wst[(n4 + 0) * 20 + kp] = f2bf(vw0.x) | (f2bf(vw1.x) << 16);
    Wst[(n4 + 1) * 20 + kp] = f2bf(vw0.y) | (f2bf(vw1.y) << 16);
    Wst[(n4 + 2) * 20 + kp] = f2bf(vw0.z) | (f2bf(vw1.z) << 16);
    Wst[(n4 + 3) * 20 + kp] = f2bf(vw0.w) | (f2bf(vw1.w) << 16);
    __syncthreads();
    if (kt < 31) {
      ap += 32;
      tp += (size_t)32 * 10240;
      va0 = *(const uint4*)ap;
      va1 = *(const uint4*)(ap + 64 * 1024);
      vw0 = *(const float4*)tp;
      vw1 = *(const float4*)(tp + 10240);
    }
    bf16x8 a0 = *(const bf16x8*)(Asm + (r0 + ml) * 40 + q * 8);
    bf16x8 a1 = *(const bf16x8*)(Asm + (r0 + 16 + ml) * 40 + q * 8);
    #pragma unroll
    for (int ct = 0; ct < 4; ct++) {
      bf16x8 b = *(const bf16x8*)((const unsigned short*)Wst +
                                  (size_t)((ct * 16 + ml) * 20 + q * 4) * 2);
      acc[0][ct] = __builtin_amdgcn_mfma_f32_16x16x32_bf16(a0, b, acc[0][ct], 0, 0, 0);
      acc[1][ct] = __builtin_amdgcn_mfma_f32_16x16x32_bf16(a1, b, acc[1][ct], 0, 0, 0);
    }
    __syncthreads();
  }

  #pragma unroll
  for (int rt = 0; rt < 2; rt++)
    #pragma unroll
    for (int ct = 0; ct < 4; ct++) {
      int col = c0 + ct * 16 + ml;
      int row = r0 + rt * 16 + q * 4;
      #pragma unroll
      for (int i = 0; i < 4; i++)
        accM[(size_t)(row + i) * 10240 + col] = (unsigned short)f2bf(acc[rt][ct][i]);
    }
}

// ---------------------------------------------------------------------------
// pairwise for one o, 256 thr, single accM plane. Grid 512. [R4-verified body]
// ---------------------------------------------------------------------------
__global__ __launch_bounds__(256, 4) void k_pairwise(
    const unsigned short* __restrict__ accM, float* __restrict__ feat)
{
  __shared__ __align__(16) char smem[12288];
  float* Ml    = (float*)smem;
  float* parts = (float*)(smem + 10240);
  const int t = threadIdx.x;
  const int o = blockIdx.x;
  {
    int i = t >> 1, kh = (t & 1) * 10;
    const unsigned short* p = accM + (size_t)i * 10240 + o * 20 + kh;
    #pragma unroll
    for (int k = 0; k < 10; k++) Ml[i * 20 + kh + k] = bf2f(p[k]);
  }
  __syncthreads();

  const int jg = t & 63, strip = t >> 6;   // 64 j-groups x 4 i-strips
  float mj[2][20];
  #pragma unroll
  for (int c = 0; c < 2; c++) {
    const float* src = Ml + (size_t)(jg * 2 + c) * 20;
    #pragma unroll
    for (int k = 0; k < 20; k++) mj[c][k] = src[k];
  }
  float acc2[2] = {0.f, 0.f};
  for (int ii = 0; ii < 32; ii++) {
    int i = strip * 32 + ii;
    const float4* m4 = (const float4*)(Ml + (size_t)i * 20);
    float mi[20];
    *(float4*)(mi + 0)  = m4[0]; *(float4*)(mi + 4)  = m4[1];
    *(float4*)(mi + 8)  = m4[2]; *(float4*)(mi + 12) = m4[3];
    *(float4*)(mi + 16) = m4[4];
    #pragma unroll
    for (int c = 0; c < 2; c++) {
      float norm = 0.f;
      #pragma unroll
      for (int k = 0; k < 20; k++) norm += fabsf(mi[k] - mj[c][k]);
      acc2[c] += __expf(-norm);
    }
  }
  parts[strip * 128 + jg * 2 + 0] = acc2[0];
  parts[strip * 128 + jg * 2 + 1] = acc2[1];
  __syncthreads();
  if (t < 128) {
    float s = parts[t] + parts[128 + t] + parts[256 + t] + parts[384 + t];
    feat[(size_t)t * 1536 + 1024 + o] = s - 1.0f;
  }
}

// ---------------------------------------------------------------------------
// final: out[r] = feat[r,:] . Wc + bc
// ---------------------------------------------------------------------------
__global__ __launch_bounds__(256) void k_final(
    const float* __restrict__ feat, const float* __restrict__ Wc,
    const float* __restrict__ bc, float* __restrict__ out)
{
  __shared__ float red[4];
  const int t = threadIdx.x, r = blockIdx.x;
  float s = 0.f;
  for (int c = t; c < 1536; c += 256) s += feat[(size_t)r * 1536 + c] * Wc[c];
  for (int off = 32; off > 0; off >>= 1) s += __shfl_down(s, off);
  if ((t & 63) == 0) red[t >> 6] = s;
  __syncthreads();
  if (t == 0) out[r] = red[0] + red[1] + red[2] + red[3] + bc[0];
}

// ---------------------------------------------------------------------------
extern "C" void kernel_launch(void* const* d_in, const int* in_sizes, int n_in,
                              void* d_out, int out_size, void* d_ws, size_t ws_size,
                              hipStream_t stream)
{
  const float* X  = (const float*)d_in[0];
  const float* W1 = (const float*)d_in[1];
  const float* b1 = (const float*)d_in[2];
  const float* W2 = (const float*)d_in[3];
  const float* b2 = (const float*)d_in[4];
  const float* W3 = (const float*)d_in[5];
  const float* b3 = (const float*)d_in[6];
  const float* T  = (const float*)d_in[7];
  const float* Wc = (const float*)d_in[8];
  const float* bc = (const float*)d_in[9];

  char* ws = (char*)d_ws;
  float*          P    = (float*)ws;
  unsigned short* accM = (unsigned short*)ws;
  unsigned short* h1hi = (unsigned short*)(ws + OFF_H1HI);
  unsigned short* h1lo = (unsigned short*)(ws + OFF_H1LO);
  unsigned short* h2hi = (unsigned short*)(ws + OFF_H2HI);
  unsigned short* h2lo = (unsigned short*)(ws + OFF_H2LO);
  unsigned short* h3hi = (unsigned short*)(ws + OFF_H3HI);
  float*          feat = (float*)(ws + OFF_FEAT);
  float*          out  = (float*)d_out;

  // L1: [128,2048] = lrelu(X @ W1 + b1), X split in-kernel; K=2048, S=8
  k_gemm1<<<dim3(32, 8), 256, 0, stream>>>(X, W1, P);
  k_reduce<<<256, 256, 0, stream>>>(P, b1, nullptr, h1hi, h1lo, 2048, 8, 0);
  // L2: [128,1024] = lrelu(h1 @ W2 + b2); K=2048, S=16
  k_gemm3<<<dim3(16, 16), 256, 0, stream>>>(h1hi, h1lo, W2, P, 2048, 1024, 128);
  k_reduce<<<128, 256, 0, stream>>>(P, b2, nullptr, h2hi, h2lo, 1024, 16, 0);
  // L3: [128,1024] = lrelu(h2 @ W3 + b3); K=1024, S=8 -> feat[:, :1024] + h3hi
  k_gemm3<<<dim3(16, 8), 256, 0, stream>>>(h2hi, h2lo, W3, P, 1024, 1024, 128);
  k_reduce<<<128, 256, 0, stream>>>(P, b3, feat, h3hi, nullptr, 1024, 8, 1536);
  // M = h3 @ T (full K) -> accM bf16 [128][10240]
  k_gemm4<<<160, 256, 0, stream>>>(h3hi, T, accM);
  // minibatch discrimination -> feat[:, 1024:]
  k_pairwise<<<512, 256, 0, stream>>>(accM, feat);
  // out = feat @ Wc + bc
  k_final<<<128, 256, 0, stream>>>(feat, Wc, bc, out);
}

// Round 7
// 182.341 us; speedup vs baseline: 4.6552x; 1.0458x over previous
//
#include <hip/hip_runtime.h>
#include <hip/hip_bf16.h>

// ---------------------------------------------------------------------------
// 8-kernel pipeline. All compute bodies harness-verified in R2/R5/R6.
//  k_gemm1   : L1 = lrelu(X@W1+b1); X fp32 split->hi/lo bf16 in LDS staging;
//              3-split MFMA (Ahi*Whi + Ahi*Wlo + Alo*Whi); split-K 8 -> P
//  k_reduce  : partial-sum + bias + lrelu -> bf16 hi/lo planes (L1, L2)
//  k_gemm3 x2: L2/L3 gemms on pre-split bf16 planes, split-K -> P
//  k_reduce3 : L3 epilogue, block-per-row: h3hi plane + out[r]=h3.Wc[:1024]+bc
//  k_gemm4   : M = h3 @ T, split-2 K (grid 320) -> accM bf16 [2][128][10240]
//  k_pairwise: 512 thr/o; o_b[j] -> atomicAdd((o_b-1)*Wc[1024+o]) into out
// R4/R5 lesson: persistent-kernel grid barriers cost 60-78us on MI355X ->
// multi-kernel. R6 lesson: gemm4 at 160 blocks starves the grid -> split-2.
// ws layout (bytes):
//   [0, 8388608)         P fp32 partials (<=8MB) / accM bf16 [2] (5.24MB)
//   [8388608, 8912896)   h1hi 128x2048 bf16
//   [8912896, 9437184)   h1lo
//   [9437184, 9699328)   h2hi 128x1024 bf16
//   [9699328, 9961472)   h2lo
//   [9961472, 10223616)  h3hi
// ---------------------------------------------------------------------------

typedef __bf16 bf16x8 __attribute__((ext_vector_type(8)));
typedef __bf16 bf16x2 __attribute__((ext_vector_type(2)));
typedef float  f32x4  __attribute__((ext_vector_type(4)));

#define OFF_H1HI 8388608
#define OFF_H1LO 8912896
#define OFF_H2HI 9437184
#define OFF_H2LO 9699328
#define OFF_H3HI 9961472

static __device__ __forceinline__ unsigned int f2bf(float f) {
  union { float f; unsigned int u; } v; v.f = f;
  unsigned int r = v.u + 0x7FFFu + ((v.u >> 16) & 1u);   // RNE to bf16
  return r >> 16;
}
static __device__ __forceinline__ float bf2f(unsigned short u) {
  union { unsigned int u; float f; } v; v.u = ((unsigned int)u) << 16;
  return v.f;
}
static __device__ __forceinline__ unsigned int pack_bf16_rne(float a, float b) {
  bf16x2 v; v[0] = (__bf16)a; v[1] = (__bf16)b;
  return __builtin_bit_cast(unsigned int, v);
}
static __device__ __forceinline__ float lrelu(float x) {
  return x >= 0.0f ? x : 0.01f * x;
}
// 8 fp32 -> bf16 hi plane (uint4) + lo plane (uint4)
static __device__ __forceinline__ void split8(const float* x, uint4& h, uint4& l) {
  unsigned* hp = (unsigned*)&h; unsigned* lp = (unsigned*)&l;
  #pragma unroll
  for (int i = 0; i < 4; i++) {
    float x0 = x[2 * i], x1 = x[2 * i + 1];
    unsigned hu = pack_bf16_rne(x0, x1);
    float f0 = bf2f((unsigned short)(hu & 0xFFFFu));
    float f1 = bf2f((unsigned short)(hu >> 16));
    hp[i] = hu;
    lp[i] = pack_bf16_rne(x0 - f0, x1 - f1);
  }
}

// ---------------------------------------------------------------------------
// L1 gemm: A = X fp32, split hi/lo during LDS staging. Tile 128x64, k-tile 32,
// kchunk 256 (8 k-tiles). Grid (32, 8). [R5/R6-verified body]
// ---------------------------------------------------------------------------
__global__ __launch_bounds__(256, 2) void k_gemm1(
    const float* __restrict__ X, const float* __restrict__ W,
    float* __restrict__ P)
{
  __shared__ __align__(16) char smem[30720];
  unsigned short* AHs = (unsigned short*)smem;            // [128][40]
  unsigned short* ALs = (unsigned short*)(smem + 10240);
  unsigned int*   WHs = (unsigned int*)(smem + 20480);    // [64][20]
  unsigned int*   WLs = (unsigned int*)(smem + 25600);
  const int t     = threadIdx.x;
  const int c0    = blockIdx.x * 64;
  const int kbase = blockIdx.y * 256;
  const int lane  = t & 63, wave = t >> 6;
  const int ml    = lane & 15, q = lane >> 4;
  const int r0    = wave * 32;
  const int ra = t >> 2, qa = t & 3;
  const int kp = t & 15, n4 = (t >> 4) * 4;

  f32x4 acc[2][4];
  #pragma unroll
  for (int i = 0; i < 2; i++)
    #pragma unroll
    for (int j = 0; j < 4; j++) acc[i][j] = (f32x4){0.f, 0.f, 0.f, 0.f};

  const float* xp0 = X + (size_t)ra * 2048 + kbase + qa * 8;
  const float* xp1 = xp0 + (size_t)64 * 2048;
  const float* wp  = W + (size_t)(kbase + 2 * kp) * 2048 + c0 + n4;
  float xr0[8], xr1[8];
  *(float4*)(xr0 + 0) = *(const float4*)xp0;
  *(float4*)(xr0 + 4) = *(const float4*)(xp0 + 4);
  *(float4*)(xr1 + 0) = *(const float4*)xp1;
  *(float4*)(xr1 + 4) = *(const float4*)(xp1 + 4);
  float4 vw0 = *(const float4*)wp;
  float4 vw1 = *(const float4*)(wp + 2048);

  for (int kt = 0; kt < 8; kt++) {
    uint4 h0, l0, h1, l1;
    split8(xr0, h0, l0); split8(xr1, h1, l1);
    *(uint4*)(AHs + ra * 40 + qa * 8)        = h0;
    *(uint4*)(AHs + (ra + 64) * 40 + qa * 8) = h1;
    *(uint4*)(ALs + ra * 40 + qa * 8)        = l0;
    *(uint4*)(ALs + (ra + 64) * 40 + qa * 8) = l1;
    {
      float w0[4], w1[4];
      *(float4*)w0 = vw0; *(float4*)w1 = vw1;
      #pragma unroll
      for (int c = 0; c < 4; c++) {
        unsigned int hu = pack_bf16_rne(w0[c], w1[c]);
        float f0 = bf2f((unsigned short)(hu & 0xFFFFu));
        float f1 = bf2f((unsigned short)(hu >> 16));
        unsigned int lu = pack_bf16_rne(w0[c] - f0, w1[c] - f1);
        WHs[(n4 + c) * 20 + kp] = hu;
        WLs[(n4 + c) * 20 + kp] = lu;
      }
    }
    __syncthreads();
    if (kt < 7) {
      xp0 += 32; xp1 += 32;
      wp  += (size_t)32 * 2048;
      *(float4*)(xr0 + 0) = *(const float4*)xp0;
      *(float4*)(xr0 + 4) = *(const float4*)(xp0 + 4);
      *(float4*)(xr1 + 0) = *(const float4*)xp1;
      *(float4*)(xr1 + 4) = *(const float4*)(xp1 + 4);
      vw0 = *(const float4*)wp;
      vw1 = *(const float4*)(wp + 2048);
    }
    bf16x8 ah0 = *(const bf16x8*)(AHs + (r0 + ml) * 40 + q * 8);
    bf16x8 ah1 = *(const bf16x8*)(AHs + (r0 + 16 + ml) * 40 + q * 8);
    bf16x8 al0 = *(const bf16x8*)(ALs + (r0 + ml) * 40 + q * 8);
    bf16x8 al1 = *(const bf16x8*)(ALs + (r0 + 16 + ml) * 40 + q * 8);
    #pragma unroll
    for (int ct = 0; ct < 4; ct++) {
      bf16x8 bh = *(const bf16x8*)((const unsigned short*)WHs +
                                   (size_t)((ct * 16 + ml) * 20 + q * 4) * 2);
      bf16x8 bl = *(const bf16x8*)((const unsigned short*)WLs +
                                   (size_t)((ct * 16 + ml) * 20 + q * 4) * 2);
      acc[0][ct] = __builtin_amdgcn_mfma_f32_16x16x32_bf16(ah0, bh, acc[0][ct], 0, 0, 0);
      acc[1][ct] = __builtin_amdgcn_mfma_f32_16x16x32_bf16(ah1, bh, acc[1][ct], 0, 0, 0);
      acc[0][ct] = __builtin_amdgcn_mfma_f32_16x16x32_bf16(ah0, bl, acc[0][ct], 0, 0, 0);
      acc[1][ct] = __builtin_amdgcn_mfma_f32_16x16x32_bf16(ah1, bl, acc[1][ct], 0, 0, 0);
      acc[0][ct] = __builtin_amdgcn_mfma_f32_16x16x32_bf16(al0, bh, acc[0][ct], 0, 0, 0);
      acc[1][ct] = __builtin_amdgcn_mfma_f32_16x16x32_bf16(al1, bh, acc[1][ct], 0, 0, 0);
    }
    __syncthreads();
  }

  float* op = P + (size_t)blockIdx.y * 128 * 2048;
  #pragma unroll
  for (int rt = 0; rt < 2; rt++)
    #pragma unroll
    for (int ct = 0; ct < 4; ct++) {
      const int col = c0 + ct * 16 + ml;
      const int row = r0 + rt * 16 + q * 4;
      #pragma unroll
      for (int i = 0; i < 4; i++)
        op[(size_t)(row + i) * 2048 + col] = acc[rt][ct][i];
    }
}

// ---------------------------------------------------------------------------
// L2/L3 gemm on pre-split bf16 planes. Tile 128x64, k-tile 32, split-K.
// Grid (N/64, S). [R2-verified body]
// ---------------------------------------------------------------------------
__global__ __launch_bounds__(256, 2) void k_gemm3(
    const unsigned short* __restrict__ Ahi, const unsigned short* __restrict__ Alo,
    const float* __restrict__ W, float* __restrict__ P,
    int K, int N, int kchunk)
{
  __shared__ __align__(16) char smem[30720];
  unsigned short* AHs = (unsigned short*)smem;
  unsigned short* ALs = (unsigned short*)(smem + 10240);
  unsigned int*   WHs = (unsigned int*)(smem + 20480);
  unsigned int*   WLs = (unsigned int*)(smem + 25600);
  const int t     = threadIdx.x;
  const int c0    = blockIdx.x * 64;
  const int kbase = blockIdx.y * kchunk;
  const int lane  = t & 63, wave = t >> 6;
  const int ml    = lane & 15, q = lane >> 4;
  const int r0    = wave * 32;
  const int ra = t >> 2, qa = t & 3;
  const int kp = t & 15, n4 = (t >> 4) * 4;

  f32x4 acc[2][4];
  #pragma unroll
  for (int i = 0; i < 2; i++)
    #pragma unroll
    for (int j = 0; j < 4; j++) acc[i][j] = (f32x4){0.f, 0.f, 0.f, 0.f};

  const unsigned short* ahp = Ahi + (size_t)ra * K + kbase + qa * 8;
  const unsigned short* alp = Alo + (size_t)ra * K + kbase + qa * 8;
  const float*          wp  = W + (size_t)(kbase + 2 * kp) * N + c0 + n4;
  uint4  vah0 = *(const uint4*)ahp;
  uint4  vah1 = *(const uint4*)(ahp + (size_t)64 * K);
  uint4  val0 = *(const uint4*)alp;
  uint4  val1 = *(const uint4*)(alp + (size_t)64 * K);
  float4 vw0 = *(const float4*)wp;
  float4 vw1 = *(const float4*)(wp + N);

  const int nkt = kchunk >> 5;
  for (int kt = 0; kt < nkt; kt++) {
    *(uint4*)(AHs + ra * 40 + qa * 8)        = vah0;
    *(uint4*)(AHs + (ra + 64) * 40 + qa * 8) = vah1;
    *(uint4*)(ALs + ra * 40 + qa * 8)        = val0;
    *(uint4*)(ALs + (ra + 64) * 40 + qa * 8) = val1;
    {
      float w0[4], w1[4];
      *(float4*)w0 = vw0; *(float4*)w1 = vw1;
      #pragma unroll
      for (int c = 0; c < 4; c++) {
        unsigned int hu = pack_bf16_rne(w0[c], w1[c]);
        float f0 = bf2f((unsigned short)(hu & 0xFFFFu));
        float f1 = bf2f((unsigned short)(hu >> 16));
        unsigned int lu = pack_bf16_rne(w0[c] - f0, w1[c] - f1);
        WHs[(n4 + c) * 20 + kp] = hu;
        WLs[(n4 + c) * 20 + kp] = lu;
      }
    }
    __syncthreads();
    if (kt + 1 < nkt) {
      ahp += 32; alp += 32;
      wp  += (size_t)32 * N;
      vah0 = *(const uint4*)ahp;
      vah1 = *(const uint4*)(ahp + (size_t)64 * K);
      val0 = *(const uint4*)alp;
      val1 = *(const uint4*)(alp + (size_t)64 * K);
      vw0 = *(const float4*)wp;
      vw1 = *(const float4*)(wp + N);
    }
    bf16x8 ah0 = *(const bf16x8*)(AHs + (r0 + ml) * 40 + q * 8);
    bf16x8 ah1 = *(const bf16x8*)(AHs + (r0 + 16 + ml) * 40 + q * 8);
    bf16x8 al0 = *(const bf16x8*)(ALs + (r0 + ml) * 40 + q * 8);
    bf16x8 al1 = *(const bf16x8*)(ALs + (r0 + 16 + ml) * 40 + q * 8);
    #pragma unroll
    for (int ct = 0; ct < 4; ct++) {
      bf16x8 bh = *(const bf16x8*)((const unsigned short*)WHs +
                                   (size_t)((ct * 16 + ml) * 20 + q * 4) * 2);
      bf16x8 bl = *(const bf16x8*)((const unsigned short*)WLs +
                                   (size_t)((ct * 16 + ml) * 20 + q * 4) * 2);
      acc[0][ct] = __builtin_amdgcn_mfma_f32_16x16x32_bf16(ah0, bh, acc[0][ct], 0, 0, 0);
      acc[1][ct] = __builtin_amdgcn_mfma_f32_16x16x32_bf16(ah1, bh, acc[1][ct], 0, 0, 0);
      acc[0][ct] = __builtin_amdgcn_mfma_f32_16x16x32_bf16(ah0, bl, acc[0][ct], 0, 0, 0);
      acc[1][ct] = __builtin_amdgcn_mfma_f32_16x16x32_bf16(ah1, bl, acc[1][ct], 0, 0, 0);
      acc[0][ct] = __builtin_amdgcn_mfma_f32_16x16x32_bf16(al0, bh, acc[0][ct], 0, 0, 0);
      acc[1][ct] = __builtin_amdgcn_mfma_f32_16x16x32_bf16(al1, bh, acc[1][ct], 0, 0, 0);
    }
    __syncthreads();
  }

  float* op = P + (size_t)blockIdx.y * 128 * N;
  #pragma unroll
  for (int rt = 0; rt < 2; rt++)
    #pragma unroll
    for (int ct = 0; ct < 4; ct++) {
      const int col = c0 + ct * 16 + ml;
      const int row = r0 + rt * 16 + q * 4;
      #pragma unroll
      for (int i = 0; i < 4; i++)
        op[(size_t)(row + i) * N + col] = acc[rt][ct][i];
    }
}

// ---------------------------------------------------------------------------
// Sum S partials + bias + LeakyReLU -> bf16 hi/lo planes (layers 1, 2).
// ---------------------------------------------------------------------------
__global__ __launch_bounds__(256) void k_reduce(
    const float* __restrict__ P, const float* __restrict__ bias,
    unsigned short* __restrict__ outHi, unsigned short* __restrict__ outLo,
    int N, int S)
{
  const int gid = blockIdx.x * 256 + threadIdx.x;
  const int c4 = N >> 2;
  if (gid >= 128 * c4) return;
  const int r = gid / c4;
  const int c = (gid - r * c4) * 4;
  float4 s = make_float4(0, 0, 0, 0);
  for (int si = 0; si < S; si++) {
    float4 p = *(const float4*)(P + (size_t)si * 128 * N + (size_t)r * N + c);
    s.x += p.x; s.y += p.y; s.z += p.z; s.w += p.w;
  }
  float4 b = *(const float4*)(bias + c);
  s.x = lrelu(s.x + b.x); s.y = lrelu(s.y + b.y);
  s.z = lrelu(s.z + b.z); s.w = lrelu(s.w + b.w);
  ushort4 uh;
  uh.x = (unsigned short)f2bf(s.x); uh.y = (unsigned short)f2bf(s.y);
  uh.z = (unsigned short)f2bf(s.z); uh.w = (unsigned short)f2bf(s.w);
  *(ushort4*)(outHi + (size_t)r * N + c) = uh;
  ushort4 ul;
  ul.x = (unsigned short)f2bf(s.x - bf2f(uh.x));
  ul.y = (unsigned short)f2bf(s.y - bf2f(uh.y));
  ul.z = (unsigned short)f2bf(s.z - bf2f(uh.z));
  ul.w = (unsigned short)f2bf(s.w - bf2f(uh.w));
  *(ushort4*)(outLo + (size_t)r * N + c) = ul;
}

// ---------------------------------------------------------------------------
// L3 epilogue, one block per row r (grid 128 x 256 thr, 4 cols/thread):
// h3 = lrelu(sum P + b3); write h3hi bf16 plane; out[r] = h3 . Wc[:1024] + bc.
// Single writer of out[r]; pairwise later atomicAdds the o_b part.
// ---------------------------------------------------------------------------
__global__ __launch_bounds__(256) void k_reduce3(
    const float* __restrict__ P, const float* __restrict__ bias,
    const float* __restrict__ Wc, const float* __restrict__ bc,
    unsigned short* __restrict__ outHi, float* __restrict__ out)
{
  __shared__ float red[4];
  const int t = threadIdx.x, r = blockIdx.x;
  const int c = t * 4;
  float4 s = make_float4(0, 0, 0, 0);
  for (int si = 0; si < 8; si++) {
    float4 p = *(const float4*)(P + (size_t)si * 128 * 1024 + (size_t)r * 1024 + c);
    s.x += p.x; s.y += p.y; s.z += p.z; s.w += p.w;
  }
  float4 b = *(const float4*)(bias + c);
  s.x = lrelu(s.x + b.x); s.y = lrelu(s.y + b.y);
  s.z = lrelu(s.z + b.z); s.w = lrelu(s.w + b.w);
  ushort4 uh;
  uh.x = (unsigned short)f2bf(s.x); uh.y = (unsigned short)f2bf(s.y);
  uh.z = (unsigned short)f2bf(s.z); uh.w = (unsigned short)f2bf(s.w);
  *(ushort4*)(outHi + (size_t)r * 1024 + c) = uh;

  float4 w = *(const float4*)(Wc + c);
  float d = s.x * w.x + s.y * w.y + s.z * w.z + s.w * w.w;
  for (int off = 32; off > 0; off >>= 1) d += __shfl_down(d, off);
  if ((t & 63) == 0) red[t >> 6] = d;
  __syncthreads();
  if (t == 0) out[r] = red[0] + red[1] + red[2] + red[3] + bc[0];
}

// ---------------------------------------------------------------------------
// gemm4: M = h3(bf16) @ T(fp32->bf16), split-2 over K (16 k-tiles each).
// Tile 128x64. Grid (160, 2) = 320 blocks. accM bf16 [2][128][10240].
// [R5-verified body]
// ---------------------------------------------------------------------------
__global__ __launch_bounds__(256, 2) void k_gemm4(
    const unsigned short* __restrict__ h3b, const float* __restrict__ T,
    unsigned short* __restrict__ accM)
{
  __shared__ __align__(16) char smem[15360];
  unsigned short* Asm = (unsigned short*)smem;           // [128][40]
  unsigned int*   Wst = (unsigned int*)(smem + 10240);   // [64][20]
  const int t     = threadIdx.x;
  const int c0    = blockIdx.x * 64;
  const int kbase = blockIdx.y * 512;
  const int lane = t & 63, wave = t >> 6;
  const int ml   = lane & 15, q = lane >> 4;
  const int r0   = wave * 32;
  const int ra = t >> 2, qa = t & 3;
  const int kp = t & 15, n4 = (t >> 4) * 4;

  f32x4 acc[2][4];
  #pragma unroll
  for (int i = 0; i < 2; i++)
    #pragma unroll
    for (int j = 0; j < 4; j++) acc[i][j] = (f32x4){0.f, 0.f, 0.f, 0.f};

  const unsigned short* ap = h3b + (size_t)ra * 1024 + kbase + qa * 8;
  const float*          tp = T + (size_t)(kbase + 2 * kp) * 10240 + c0 + n4;
  uint4  va0 = *(const uint4*)ap;
  uint4  va1 = *(const uint4*)(ap + 64 * 1024);
  float4 vw0 = *(const float4*)tp;
  float4 vw1 = *(const float4*)(tp + 10240);

  for (int kt = 0; kt < 16; kt++) {
    *(uint4*)(Asm + ra * 40 + qa * 8)        = va0;
    *(uint4*)(Asm + (ra + 64) * 40 + qa * 8) = va1;
    Wst[(n4 + 0) * 20 + kp] = f2bf(vw0.x) | (f2bf(vw1.x) << 16);
    Wst[(n4 + 1) * 20 + kp] = f2bf(vw0.y) | (f2bf(vw1.y) << 16);
    Wst[(n4 + 2) * 20 + kp] = f2bf(vw0.z) | (f2bf(vw1.z) << 16);
    Wst[(n4 + 3) * 20 + kp] = f2bf(vw0.w) | (f2bf(vw1.w) << 16);
    __syncthreads();
    if (kt < 15) {
      ap += 32;
      tp += (size_t)32 * 10240;
      va0 = *(const uint4*)ap;
      va1 = *(const uint4*)(ap + 64 * 1024);
      vw0 = *(const float4*)tp;
      vw1 = *(const float4*)(tp + 10240);
    }
    bf16x8 a0 = *(const bf16x8*)(Asm + (r0 + ml) * 40 + q * 8);
    bf16x8 a1 = *(const bf16x8*)(Asm + (r0 + 16 + ml) * 40 + q * 8);
    #pragma unroll
    for (int ct = 0; ct < 4; ct++) {
      bf16x8 b = *(const bf16x8*)((const unsigned short*)Wst +
                                  (size_t)((ct * 16 + ml) * 20 + q * 4) * 2);
      acc[0][ct] = __builtin_amdgcn_mfma_f32_16x16x32_bf16(a0, b, acc[0][ct], 0, 0, 0);
      acc[1][ct] = __builtin_amdgcn_mfma_f32_16x16x32_bf16(a1, b, acc[1][ct], 0, 0, 0);
    }
    __syncthreads();
  }

  unsigned short* outp = accM + (size_t)blockIdx.y * 1310720;
  #pragma unroll
  for (int rt = 0; rt < 2; rt++)
    #pragma unroll
    for (int ct = 0; ct < 4; ct++) {
      int col = c0 + ct * 16 + ml;
      int row = r0 + rt * 16 + q * 4;
      #pragma unroll
      for (int i = 0; i < 4; i++)
        outp[(size_t)(row + i) * 10240 + col] = (unsigned short)f2bf(acc[rt][ct][i]);
    }
}

// ---------------------------------------------------------------------------
// pairwise: one block per o (512 blocks x 512 thr), combine 2 K-splits.
// o_b[j] = sum_i exp(-sum_k |M[i,o,k]-M[j,o,k]|) - 1, then
// atomicAdd(out[j], o_b[j] * Wc[1024+o]).  [R2 512-thr structure + R5 combine]
// ---------------------------------------------------------------------------
__global__ __launch_bounds__(512, 4) void k_pairwise(
    const unsigned short* __restrict__ accM, const float* __restrict__ Wc,
    float* __restrict__ out)
{
  __shared__ __align__(16) float Ml[128 * 20];
  __shared__ float parts[8 * 128];
  const int t = threadIdx.x;
  const int o = blockIdx.x;
  const float wco = Wc[1024 + o];
  { // load + combine 2 K-splits: M[:, o, :]
    int i = t >> 2, kh = (t & 3) * 5;
    const unsigned short* p = accM + (size_t)i * 10240 + o * 20 + kh;
    #pragma unroll
    for (int k = 0; k < 5; k++)
      Ml[i * 20 + kh + k] = bf2f(p[k]) + bf2f(p[1310720 + k]);
  }
  __syncthreads();

  const int jg = t & 63, ihalf = t >> 6;   // 64 j-groups x 8 i-strips
  float mj[2][20];
  #pragma unroll
  for (int c = 0; c < 2; c++) {
    const float* src = Ml + (size_t)(jg * 2 + c) * 20;
    #pragma unroll
    for (int k = 0; k < 20; k++) mj[c][k] = src[k];
  }
  float acc2[2] = {0.f, 0.f};
  for (int ii = 0; ii < 16; ii++) {
    int i = ihalf * 16 + ii;
    const float4* m4 = (const float4*)(Ml + (size_t)i * 20);
    float mi[20];
    *(float4*)(mi + 0)  = m4[0]; *(float4*)(mi + 4)  = m4[1];
    *(float4*)(mi + 8)  = m4[2]; *(float4*)(mi + 12) = m4[3];
    *(float4*)(mi + 16) = m4[4];
    #pragma unroll
    for (int c = 0; c < 2; c++) {
      float norm = 0.f;
      #pragma unroll
      for (int k = 0; k < 20; k++) norm += fabsf(mi[k] - mj[c][k]);
      acc2[c] += __expf(-norm);
    }
  }
  parts[ihalf * 128 + jg * 2 + 0] = acc2[0];
  parts[ihalf * 128 + jg * 2 + 1] = acc2[1];
  __syncthreads();
  if (t < 128) {
    float s = 0.f;
    #pragma unroll
    for (int ih = 0; ih < 8; ih++) s += parts[ih * 128 + t];
    atomicAdd(&out[t], (s - 1.0f) * wco);
  }
}

// ---------------------------------------------------------------------------
extern "C" void kernel_launch(void* const* d_in, const int* in_sizes, int n_in,
                              void* d_out, int out_size, void* d_ws, size_t ws_size,
                              hipStream_t stream)
{
  const float* X  = (const float*)d_in[0];
  const float* W1 = (const float*)d_in[1];
  const float* b1 = (const float*)d_in[2];
  const float* W2 = (const float*)d_in[3];
  const float* b2 = (const float*)d_in[4];
  const float* W3 = (const float*)d_in[5];
  const float* b3 = (const float*)d_in[6];
  const float* T  = (const float*)d_in[7];
  const float* Wc = (const float*)d_in[8];
  const float* bc = (const float*)d_in[9];

  char* ws = (char*)d_ws;
  float*          P    = (float*)ws;
  unsigned short* accM = (unsigned short*)ws;
  unsigned short* h1hi = (unsigned short*)(ws + OFF_H1HI);
  unsigned short* h1lo = (unsigned short*)(ws + OFF_H1LO);
  unsigned short* h2hi = (unsigned short*)(ws + OFF_H2HI);
  unsigned short* h2lo = (unsigned short*)(ws + OFF_H2LO);
  unsigned short* h3hi = (unsigned short*)(ws + OFF_H3HI);
  float*          out  = (float*)d_out;

  // L1: [128,2048] = lrelu(X @ W1 + b1), X split in-kernel; K=2048, S=8
  k_gemm1<<<dim3(32, 8), 256, 0, stream>>>(X, W1, P);
  k_reduce<<<256, 256, 0, stream>>>(P, b1, h1hi, h1lo, 2048, 8);
  // L2: [128,1024] = lrelu(h1 @ W2 + b2); K=2048, S=16
  k_gemm3<<<dim3(16, 16), 256, 0, stream>>>(h1hi, h1lo, W2, P, 2048, 1024, 128);
  k_reduce<<<128, 256, 0, stream>>>(P, b2, h2hi, h2lo, 1024, 16);
  // L3: [128,1024] = lrelu(h2 @ W3 + b3); K=1024, S=8
  k_gemm3<<<dim3(16, 8), 256, 0, stream>>>(h2hi, h2lo, W3, P, 1024, 1024, 128);
  // L3 epilogue: h3hi plane + out[r] = h3 . Wc[:1024] + bc  (single writer)
  k_reduce3<<<128, 256, 0, stream>>>(P, b3, Wc, bc, h3hi, out);
  // M = h3 @ T, split-2 -> accM bf16 [2][128][10240]
  k_gemm4<<<dim3(160, 2), 256, 0, stream>>>(h3hi, T, accM);
  // minibatch discrimination: atomicAdd o_b contributions into out
  k_pairwise<<<512, 512, 0, stream>>>(accM, Wc, out);
}

// Round 8
// 178.815 us; speedup vs baseline: 4.7470x; 1.0197x over previous
//
#include <hip/hip_runtime.h>
#include <hip/hip_bf16.h>

// ---------------------------------------------------------------------------
// 8-kernel pipeline; every body harness-verified (R2/R5/R6/R7).
//  k_gemm1   : L1 = lrelu(X@W1+b1); X fp32 split->hi/lo bf16 in LDS staging;
//              3-split MFMA (Ahi*Whi + Ahi*Wlo + Alo*Whi); split-K 8 -> P
//  k_reduce  : partial-sum + bias + lrelu -> bf16 hi/lo planes (L1, L2)
//  k_gemm3 x2: L2/L3 gemms on pre-split bf16 planes, split-K -> P
//  k_reduce3 : L3 epilogue per-row: h3hi plane + out[r] = h3.Wc[:1024] + bc
//  k_gemm4   : M = h3 @ T, split-4 K (grid 640: R6/R7 lesson - grid
//              parallelism beats accM traffic for tiny-M) -> accM bf16 [4]
//  k_pairwise: 512 thr/o, combine 4 splits; atomicAdd (o_b-1)*Wc[1024+o]
// Session facts: persistent-kernel grid barrier = 60-78us on MI355X (dead);
// total time ~invariant to kernel count => ~160us fixed harness floor;
// our controllable work ~25us, traffic floor ~15us.
// ws layout (bytes):
//   [0, 10485760)          P fp32 partials (<=8MB) / accM bf16 [4] (10.49MB)
//   [10485760, 11010048)   h1hi 128x2048 bf16
//   [11010048, 11534336)   h1lo
//   [11534336, 11796480)   h2hi 128x1024 bf16
//   [11796480, 12058624)   h2lo
//   [12058624, 12320768)   h3hi   (above accM region: alive during gemm4)
// ---------------------------------------------------------------------------

typedef __bf16 bf16x8 __attribute__((ext_vector_type(8)));
typedef __bf16 bf16x2 __attribute__((ext_vector_type(2)));
typedef float  f32x4  __attribute__((ext_vector_type(4)));

#define OFF_H1HI 10485760
#define OFF_H1LO 11010048
#define OFF_H2HI 11534336
#define OFF_H2LO 11796480
#define OFF_H3HI 12058624

static __device__ __forceinline__ unsigned int f2bf(float f) {
  union { float f; unsigned int u; } v; v.f = f;
  unsigned int r = v.u + 0x7FFFu + ((v.u >> 16) & 1u);   // RNE to bf16
  return r >> 16;
}
static __device__ __forceinline__ float bf2f(unsigned short u) {
  union { unsigned int u; float f; } v; v.u = ((unsigned int)u) << 16;
  return v.f;
}
static __device__ __forceinline__ unsigned int pack_bf16_rne(float a, float b) {
  bf16x2 v; v[0] = (__bf16)a; v[1] = (__bf16)b;
  return __builtin_bit_cast(unsigned int, v);
}
static __device__ __forceinline__ float lrelu(float x) {
  return x >= 0.0f ? x : 0.01f * x;
}
// 8 fp32 -> bf16 hi plane (uint4) + lo plane (uint4)
static __device__ __forceinline__ void split8(const float* x, uint4& h, uint4& l) {
  unsigned* hp = (unsigned*)&h; unsigned* lp = (unsigned*)&l;
  #pragma unroll
  for (int i = 0; i < 4; i++) {
    float x0 = x[2 * i], x1 = x[2 * i + 1];
    unsigned hu = pack_bf16_rne(x0, x1);
    float f0 = bf2f((unsigned short)(hu & 0xFFFFu));
    float f1 = bf2f((unsigned short)(hu >> 16));
    hp[i] = hu;
    lp[i] = pack_bf16_rne(x0 - f0, x1 - f1);
  }
}

// ---------------------------------------------------------------------------
// L1 gemm: A = X fp32, split hi/lo during LDS staging. Tile 128x64, k-tile 32,
// kchunk 256 (8 k-tiles). Grid (32, 8). [R5/R6/R7-verified body]
// ---------------------------------------------------------------------------
__global__ __launch_bounds__(256, 2) void k_gemm1(
    const float* __restrict__ X, const float* __restrict__ W,
    float* __restrict__ P)
{
  __shared__ __align__(16) char smem[30720];
  unsigned short* AHs = (unsigned short*)smem;            // [128][40]
  unsigned short* ALs = (unsigned short*)(smem + 10240);
  unsigned int*   WHs = (unsigned int*)(smem + 20480);    // [64][20]
  unsigned int*   WLs = (unsigned int*)(smem + 25600);
  const int t     = threadIdx.x;
  const int c0    = blockIdx.x * 64;
  const int kbase = blockIdx.y * 256;
  const int lane  = t & 63, wave = t >> 6;
  const int ml    = lane & 15, q = lane >> 4;
  const int r0    = wave * 32;
  const int ra = t >> 2, qa = t & 3;
  const int kp = t & 15, n4 = (t >> 4) * 4;

  f32x4 acc[2][4];
  #pragma unroll
  for (int i = 0; i < 2; i++)
    #pragma unroll
    for (int j = 0; j < 4; j++) acc[i][j] = (f32x4){0.f, 0.f, 0.f, 0.f};

  const float* xp0 = X + (size_t)ra * 2048 + kbase + qa * 8;
  const float* xp1 = xp0 + (size_t)64 * 2048;
  const float* wp  = W + (size_t)(kbase + 2 * kp) * 2048 + c0 + n4;
  float xr0[8], xr1[8];
  *(float4*)(xr0 + 0) = *(const float4*)xp0;
  *(float4*)(xr0 + 4) = *(const float4*)(xp0 + 4);
  *(float4*)(xr1 + 0) = *(const float4*)xp1;
  *(float4*)(xr1 + 4) = *(const float4*)(xp1 + 4);
  float4 vw0 = *(const float4*)wp;
  float4 vw1 = *(const float4*)(wp + 2048);

  for (int kt = 0; kt < 8; kt++) {
    uint4 h0, l0, h1, l1;
    split8(xr0, h0, l0); split8(xr1, h1, l1);
    *(uint4*)(AHs + ra * 40 + qa * 8)        = h0;
    *(uint4*)(AHs + (ra + 64) * 40 + qa * 8) = h1;
    *(uint4*)(ALs + ra * 40 + qa * 8)        = l0;
    *(uint4*)(ALs + (ra + 64) * 40 + qa * 8) = l1;
    {
      float w0[4], w1[4];
      *(float4*)w0 = vw0; *(float4*)w1 = vw1;
      #pragma unroll
      for (int c = 0; c < 4; c++) {
        unsigned int hu = pack_bf16_rne(w0[c], w1[c]);
        float f0 = bf2f((unsigned short)(hu & 0xFFFFu));
        float f1 = bf2f((unsigned short)(hu >> 16));
        unsigned int lu = pack_bf16_rne(w0[c] - f0, w1[c] - f1);
        WHs[(n4 + c) * 20 + kp] = hu;
        WLs[(n4 + c) * 20 + kp] = lu;
      }
    }
    __syncthreads();
    if (kt < 7) {
      xp0 += 32; xp1 += 32;
      wp  += (size_t)32 * 2048;
      *(float4*)(xr0 + 0) = *(const float4*)xp0;
      *(float4*)(xr0 + 4) = *(const float4*)(xp0 + 4);
      *(float4*)(xr1 + 0) = *(const float4*)xp1;
      *(float4*)(xr1 + 4) = *(const float4*)(xp1 + 4);
      vw0 = *(const float4*)wp;
      vw1 = *(const float4*)(wp + 2048);
    }
    bf16x8 ah0 = *(const bf16x8*)(AHs + (r0 + ml) * 40 + q * 8);
    bf16x8 ah1 = *(const bf16x8*)(AHs + (r0 + 16 + ml) * 40 + q * 8);
    bf16x8 al0 = *(const bf16x8*)(ALs + (r0 + ml) * 40 + q * 8);
    bf16x8 al1 = *(const bf16x8*)(ALs + (r0 + 16 + ml) * 40 + q * 8);
    #pragma unroll
    for (int ct = 0; ct < 4; ct++) {
      bf16x8 bh = *(const bf16x8*)((const unsigned short*)WHs +
                                   (size_t)((ct * 16 + ml) * 20 + q * 4) * 2);
      bf16x8 bl = *(const bf16x8*)((const unsigned short*)WLs +
                                   (size_t)((ct * 16 + ml) * 20 + q * 4) * 2);
      acc[0][ct] = __builtin_amdgcn_mfma_f32_16x16x32_bf16(ah0, bh, acc[0][ct], 0, 0, 0);
      acc[1][ct] = __builtin_amdgcn_mfma_f32_16x16x32_bf16(ah1, bh, acc[1][ct], 0, 0, 0);
      acc[0][ct] = __builtin_amdgcn_mfma_f32_16x16x32_bf16(ah0, bl, acc[0][ct], 0, 0, 0);
      acc[1][ct] = __builtin_amdgcn_mfma_f32_16x16x32_bf16(ah1, bl, acc[1][ct], 0, 0, 0);
      acc[0][ct] = __builtin_amdgcn_mfma_f32_16x16x32_bf16(al0, bh, acc[0][ct], 0, 0, 0);
      acc[1][ct] = __builtin_amdgcn_mfma_f32_16x16x32_bf16(al1, bh, acc[1][ct], 0, 0, 0);
    }
    __syncthreads();
  }

  float* op = P + (size_t)blockIdx.y * 128 * 2048;
  #pragma unroll
  for (int rt = 0; rt < 2; rt++)
    #pragma unroll
    for (int ct = 0; ct < 4; ct++) {
      const int col = c0 + ct * 16 + ml;
      const int row = r0 + rt * 16 + q * 4;
      #pragma unroll
      for (int i = 0; i < 4; i++)
        op[(size_t)(row + i) * 2048 + col] = acc[rt][ct][i];
    }
}

// ---------------------------------------------------------------------------
// L2/L3 gemm on pre-split bf16 planes. Tile 128x64, k-tile 32, split-K.
// Grid (N/64, S). [R2-verified body]
// ---------------------------------------------------------------------------
__global__ __launch_bounds__(256, 2) void k_gemm3(
    const unsigned short* __restrict__ Ahi, const unsigned short* __restrict__ Alo,
    const float* __restrict__ W, float* __restrict__ P,
    int K, int N, int kchunk)
{
  __shared__ __align__(16) char smem[30720];
  unsigned short* AHs = (unsigned short*)smem;
  unsigned short* ALs = (unsigned short*)(smem + 10240);
  unsigned int*   WHs = (unsigned int*)(smem + 20480);
  unsigned int*   WLs = (unsigned int*)(smem + 25600);
  const int t     = threadIdx.x;
  const int c0    = blockIdx.x * 64;
  const int kbase = blockIdx.y * kchunk;
  const int lane  = t & 63, wave = t >> 6;
  const int ml    = lane & 15, q = lane >> 4;
  const int r0    = wave * 32;
  const int ra = t >> 2, qa = t & 3;
  const int kp = t & 15, n4 = (t >> 4) * 4;

  f32x4 acc[2][4];
  #pragma unroll
  for (int i = 0; i < 2; i++)
    #pragma unroll
    for (int j = 0; j < 4; j++) acc[i][j] = (f32x4){0.f, 0.f, 0.f, 0.f};

  const unsigned short* ahp = Ahi + (size_t)ra * K + kbase + qa * 8;
  const unsigned short* alp = Alo + (size_t)ra * K + kbase + qa * 8;
  const float*          wp  = W + (size_t)(kbase + 2 * kp) * N + c0 + n4;
  uint4  vah0 = *(const uint4*)ahp;
  uint4  vah1 = *(const uint4*)(ahp + (size_t)64 * K);
  uint4  val0 = *(const uint4*)alp;
  uint4  val1 = *(const uint4*)(alp + (size_t)64 * K);
  float4 vw0 = *(const float4*)wp;
  float4 vw1 = *(const float4*)(wp + N);

  const int nkt = kchunk >> 5;
  for (int kt = 0; kt < nkt; kt++) {
    *(uint4*)(AHs + ra * 40 + qa * 8)        = vah0;
    *(uint4*)(AHs + (ra + 64) * 40 + qa * 8) = vah1;
    *(uint4*)(ALs + ra * 40 + qa * 8)        = val0;
    *(uint4*)(ALs + (ra + 64) * 40 + qa * 8) = val1;
    {
      float w0[4], w1[4];
      *(float4*)w0 = vw0; *(float4*)w1 = vw1;
      #pragma unroll
      for (int c = 0; c < 4; c++) {
        unsigned int hu = pack_bf16_rne(w0[c], w1[c]);
        float f0 = bf2f((unsigned short)(hu & 0xFFFFu));
        float f1 = bf2f((unsigned short)(hu >> 16));
        unsigned int lu = pack_bf16_rne(w0[c] - f0, w1[c] - f1);
        WHs[(n4 + c) * 20 + kp] = hu;
        WLs[(n4 + c) * 20 + kp] = lu;
      }
    }
    __syncthreads();
    if (kt + 1 < nkt) {
      ahp += 32; alp += 32;
      wp  += (size_t)32 * N;
      vah0 = *(const uint4*)ahp;
      vah1 = *(const uint4*)(ahp + (size_t)64 * K);
      val0 = *(const uint4*)alp;
      val1 = *(const uint4*)(alp + (size_t)64 * K);
      vw0 = *(const float4*)wp;
      vw1 = *(const float4*)(wp + N);
    }
    bf16x8 ah0 = *(const bf16x8*)(AHs + (r0 + ml) * 40 + q * 8);
    bf16x8 ah1 = *(const bf16x8*)(AHs + (r0 + 16 + ml) * 40 + q * 8);
    bf16x8 al0 = *(const bf16x8*)(ALs + (r0 + ml) * 40 + q * 8);
    bf16x8 al1 = *(const bf16x8*)(ALs + (r0 + 16 + ml) * 40 + q * 8);
    #pragma unroll
    for (int ct = 0; ct < 4; ct++) {
      bf16x8 bh = *(const bf16x8*)((const unsigned short*)WHs +
                                   (size_t)((ct * 16 + ml) * 20 + q * 4) * 2);
      bf16x8 bl = *(const bf16x8*)((const unsigned short*)WLs +
                                   (size_t)((ct * 16 + ml) * 20 + q * 4) * 2);
      acc[0][ct] = __builtin_amdgcn_mfma_f32_16x16x32_bf16(ah0, bh, acc[0][ct], 0, 0, 0);
      acc[1][ct] = __builtin_amdgcn_mfma_f32_16x16x32_bf16(ah1, bh, acc[1][ct], 0, 0, 0);
      acc[0][ct] = __builtin_amdgcn_mfma_f32_16x16x32_bf16(ah0, bl, acc[0][ct], 0, 0, 0);
      acc[1][ct] = __builtin_amdgcn_mfma_f32_16x16x32_bf16(ah1, bl, acc[1][ct], 0, 0, 0);
      acc[0][ct] = __builtin_amdgcn_mfma_f32_16x16x32_bf16(al0, bh, acc[0][ct], 0, 0, 0);
      acc[1][ct] = __builtin_amdgcn_mfma_f32_16x16x32_bf16(al1, bh, acc[1][ct], 0, 0, 0);
    }
    __syncthreads();
  }

  float* op = P + (size_t)blockIdx.y * 128 * N;
  #pragma unroll
  for (int rt = 0; rt < 2; rt++)
    #pragma unroll
    for (int ct = 0; ct < 4; ct++) {
      const int col = c0 + ct * 16 + ml;
      const int row = r0 + rt * 16 + q * 4;
      #pragma unroll
      for (int i = 0; i < 4; i++)
        op[(size_t)(row + i) * N + col] = acc[rt][ct][i];
    }
}

// ---------------------------------------------------------------------------
// Sum S partials + bias + LeakyReLU -> bf16 hi/lo planes (layers 1, 2).
// ---------------------------------------------------------------------------
__global__ __launch_bounds__(256) void k_reduce(
    const float* __restrict__ P, const float* __restrict__ bias,
    unsigned short* __restrict__ outHi, unsigned short* __restrict__ outLo,
    int N, int S)
{
  const int gid = blockIdx.x * 256 + threadIdx.x;
  const int c4 = N >> 2;
  if (gid >= 128 * c4) return;
  const int r = gid / c4;
  const int c = (gid - r * c4) * 4;
  float4 s = make_float4(0, 0, 0, 0);
  for (int si = 0; si < S; si++) {
    float4 p = *(const float4*)(P + (size_t)si * 128 * N + (size_t)r * N + c);
    s.x += p.x; s.y += p.y; s.z += p.z; s.w += p.w;
  }
  float4 b = *(const float4*)(bias + c);
  s.x = lrelu(s.x + b.x); s.y = lrelu(s.y + b.y);
  s.z = lrelu(s.z + b.z); s.w = lrelu(s.w + b.w);
  ushort4 uh;
  uh.x = (unsigned short)f2bf(s.x); uh.y = (unsigned short)f2bf(s.y);
  uh.z = (unsigned short)f2bf(s.z); uh.w = (unsigned short)f2bf(s.w);
  *(ushort4*)(outHi + (size_t)r * N + c) = uh;
  ushort4 ul;
  ul.x = (unsigned short)f2bf(s.x - bf2f(uh.x));
  ul.y = (unsigned short)f2bf(s.y - bf2f(uh.y));
  ul.z = (unsigned short)f2bf(s.z - bf2f(uh.z));
  ul.w = (unsigned short)f2bf(s.w - bf2f(uh.w));
  *(ushort4*)(outLo + (size_t)r * N + c) = ul;
}

// ---------------------------------------------------------------------------
// L3 epilogue, one block per row r (grid 128 x 256 thr, 4 cols/thread):
// h3 = lrelu(sum P + b3); write h3hi bf16 plane; out[r] = h3 . Wc[:1024] + bc.
// Single writer of out[r]; pairwise later atomicAdds the o_b part.
// [R7-verified body]
// ---------------------------------------------------------------------------
__global__ __launch_bounds__(256) void k_reduce3(
    const float* __restrict__ P, const float* __restrict__ bias,
    const float* __restrict__ Wc, const float* __restrict__ bc,
    unsigned short* __restrict__ outHi, float* __restrict__ out)
{
  __shared__ float red[4];
  const int t = threadIdx.x, r = blockIdx.x;
  const int c = t * 4;
  float4 s = make_float4(0, 0, 0, 0);
  for (int si = 0; si < 8; si++) {
    float4 p = *(const float4*)(P + (size_t)si * 128 * 1024 + (size_t)r * 1024 + c);
    s.x += p.x; s.y += p.y; s.z += p.z; s.w += p.w;
  }
  float4 b = *(const float4*)(bias + c);
  s.x = lrelu(s.x + b.x); s.y = lrelu(s.y + b.y);
  s.z = lrelu(s.z + b.z); s.w = lrelu(s.w + b.w);
  ushort4 uh;
  uh.x = (unsigned short)f2bf(s.x); uh.y = (unsigned short)f2bf(s.y);
  uh.z = (unsigned short)f2bf(s.z); uh.w = (unsigned short)f2bf(s.w);
  *(ushort4*)(outHi + (size_t)r * 1024 + c) = uh;

  float4 w = *(const float4*)(Wc + c);
  float d = s.x * w.x + s.y * w.y + s.z * w.z + s.w * w.w;
  for (int off = 32; off > 0; off >>= 1) d += __shfl_down(d, off);
  if ((t & 63) == 0) red[t >> 6] = d;
  __syncthreads();
  if (t == 0) out[r] = red[0] + red[1] + red[2] + red[3] + bc[0];
}

// ---------------------------------------------------------------------------
// gemm4: M = h3(bf16) @ T(fp32->bf16), split-4 over K (8 k-tiles each).
// Tile 128x64. Grid (160, 4) = 640 blocks. accM bf16 [4][128][10240].
// [R2-verified body/config: 640 blocks beat 320/160 monotonically]
// ---------------------------------------------------------------------------
__global__ __launch_bounds__(256, 2) void k_gemm4(
    const unsigned short* __restrict__ h3b, const float* __restrict__ T,
    unsigned short* __restrict__ accM)
{
  __shared__ __align__(16) char smem[15360];
  unsigned short* Asm = (unsigned short*)smem;           // [128][40]
  unsigned int*   Wst = (unsigned int*)(smem + 10240);   // [64][20]
  const int t     = threadIdx.x;
  const int c0    = blockIdx.x * 64;
  const int kbase = blockIdx.y * 256;
  const int lane = t & 63, wave = t >> 6;
  const int ml   = lane & 15, q = lane >> 4;
  const int r0   = wave * 32;
  const int ra = t >> 2, qa = t & 3;
  const int kp = t & 15, n4 = (t >> 4) * 4;

  f32x4 acc[2][4];
  #pragma unroll
  for (int i = 0; i < 2; i++)
    #pragma unroll
    for (int j = 0; j < 4; j++) acc[i][j] = (f32x4){0.f, 0.f, 0.f, 0.f};

  const unsigned short* ap = h3b + (size_t)ra * 1024 + kbase + qa * 8;
  const float*          tp = T + (size_t)(kbase + 2 * kp) * 10240 + c0 + n4;
  uint4  va0 = *(const uint4*)ap;
  uint4  va1 = *(const uint4*)(ap + 64 * 1024);
  float4 vw0 = *(const float4*)tp;
  float4 vw1 = *(const float4*)(tp + 10240);

  for (int kt = 0; kt < 8; kt++) {
    *(uint4*)(Asm + ra * 40 + qa * 8)        = va0;
    *(uint4*)(Asm + (ra + 64) * 40 + qa * 8) = va1;
    Wst[(n4 + 0) * 20 + kp] = f2bf(vw0.x) | (f2bf(vw1.x) << 16);
    Wst[(n4 + 1) * 20 + kp] = f2bf(vw0.y) | (f2bf(vw1.y) << 16);
    Wst[(n4 + 2) * 20 + kp] = f2bf(vw0.z) | (f2bf(vw1.z) << 16);
    Wst[(n4 + 3) * 20 + kp] = f2bf(vw0.w) | (f2bf(vw1.w) << 16);
    __syncthreads();
    if (kt < 7) {
      ap += 32;
      tp += (size_t)32 * 10240;
      va0 = *(const uint4*)ap;
      va1 = *(const uint4*)(ap + 64 * 1024);
      vw0 = *(const float4*)tp;
      vw1 = *(const float4*)(tp + 10240);
    }
    bf16x8 a0 = *(const bf16x8*)(Asm + (r0 + ml) * 40 + q * 8);
    bf16x8 a1 = *(const bf16x8*)(Asm + (r0 + 16 + ml) * 40 + q * 8);
    #pragma unroll
    for (int ct = 0; ct < 4; ct++) {
      bf16x8 b = *(const bf16x8*)((const unsigned short*)Wst +
                                  (size_t)((ct * 16 + ml) * 20 + q * 4) * 2);
      acc[0][ct] = __builtin_amdgcn_mfma_f32_16x16x32_bf16(a0, b, acc[0][ct], 0, 0, 0);
      acc[1][ct] = __builtin_amdgcn_mfma_f32_16x16x32_bf16(a1, b, acc[1][ct], 0, 0, 0);
    }
    __syncthreads();
  }

  unsigned short* outp = accM + (size_t)blockIdx.y * 1310720;
  #pragma unroll
  for (int rt = 0; rt < 2; rt++)
    #pragma unroll
    for (int ct = 0; ct < 4; ct++) {
      int col = c0 + ct * 16 + ml;
      int row = r0 + rt * 16 + q * 4;
      #pragma unroll
      for (int i = 0; i < 4; i++)
        outp[(size_t)(row + i) * 10240 + col] = (unsigned short)f2bf(acc[rt][ct][i]);
    }
}

// ---------------------------------------------------------------------------
// pairwise: one block per o (512 blocks x 512 thr), combine 4 K-splits.
// o_b[j] = sum_i exp(-sum_k |M[i,o,k]-M[j,o,k]|) - 1, then
// atomicAdd(out[j], o_b[j] * Wc[1024+o]). [R2 512-thr body + R7 atomic tail]
// ---------------------------------------------------------------------------
__global__ __launch_bounds__(512, 4) void k_pairwise(
    const unsigned short* __restrict__ accM, const float* __restrict__ Wc,
    float* __restrict__ out)
{
  __shared__ __align__(16) float Ml[128 * 20];
  __shared__ float parts[8 * 128];
  const int t = threadIdx.x;
  const int o = blockIdx.x;
  const float wco = Wc[1024 + o];
  { // load + combine 4 K-splits: M[:, o, :]
    int i = t >> 2, kh = (t & 3) * 5;
    const unsigned short* p = accM + (size_t)i * 10240 + o * 20 + kh;
    #pragma unroll
    for (int k = 0; k < 5; k++)
      Ml[i * 20 + kh + k] = bf2f(p[k]) + bf2f(p[1310720 + k]) +
                            bf2f(p[2621440 + k]) + bf2f(p[3932160 + k]);
  }
  __syncthreads();

  const int jg = t & 63, ihalf = t >> 6;   // 64 j-groups x 8 i-strips
  float mj[2][20];
  #pragma unroll
  for (int c = 0; c < 2; c++) {
    const float* src = Ml + (size_t)(jg * 2 + c) * 20;
    #pragma unroll
    for (int k = 0; k < 20; k++) mj[c][k] = src[k];
  }
  float acc2[2] = {0.f, 0.f};
  for (int ii = 0; ii < 16; ii++) {
    int i = ihalf * 16 + ii;
    const float4* m4 = (const float4*)(Ml + (size_t)i * 20);
    float mi[20];
    *(float4*)(mi + 0)  = m4[0]; *(float4*)(mi + 4)  = m4[1];
    *(float4*)(mi + 8)  = m4[2]; *(float4*)(mi + 12) = m4[3];
    *(float4*)(mi + 16) = m4[4];
    #pragma unroll
    for (int c = 0; c < 2; c++) {
      float norm = 0.f;
      #pragma unroll
      for (int k = 0; k < 20; k++) norm += fabsf(mi[k] - mj[c][k]);
      acc2[c] += __expf(-norm);
    }
  }
  parts[ihalf * 128 + jg * 2 + 0] = acc2[0];
  parts[ihalf * 128 + jg * 2 + 1] = acc2[1];
  __syncthreads();
  if (t < 128) {
    float s = 0.f;
    #pragma unroll
    for (int ih = 0; ih < 8; ih++) s += parts[ih * 128 + t];
    atomicAdd(&out[t], (s - 1.0f) * wco);
  }
}

// ---------------------------------------------------------------------------
extern "C" void kernel_launch(void* const* d_in, const int* in_sizes, int n_in,
                              void* d_out, int out_size, void* d_ws, size_t ws_size,
                              hipStream_t stream)
{
  const float* X  = (const float*)d_in[0];
  const float* W1 = (const float*)d_in[1];
  const float* b1 = (const float*)d_in[2];
  const float* W2 = (const float*)d_in[3];
  const float* b2 = (const float*)d_in[4];
  const float* W3 = (const float*)d_in[5];
  const float* b3 = (const float*)d_in[6];
  const float* T  = (const float*)d_in[7];
  const float* Wc = (const float*)d_in[8];
  const float* bc = (const float*)d_in[9];

  char* ws = (char*)d_ws;
  float*          P    = (float*)ws;
  unsigned short* accM = (unsigned short*)ws;
  unsigned short* h1hi = (unsigned short*)(ws + OFF_H1HI);
  unsigned short* h1lo = (unsigned short*)(ws + OFF_H1LO);
  unsigned short* h2hi = (unsigned short*)(ws + OFF_H2HI);
  unsigned short* h2lo = (unsigned short*)(ws + OFF_H2LO);
  unsigned short* h3hi = (unsigned short*)(ws + OFF_H3HI);
  float*          out  = (float*)d_out;

  // L1: [128,2048] = lrelu(X @ W1 + b1), X split in-kernel; K=2048, S=8
  k_gemm1<<<dim3(32, 8), 256, 0, stream>>>(X, W1, P);
  k_reduce<<<256, 256, 0, stream>>>(P, b1, h1hi, h1lo, 2048, 8);
  // L2: [128,1024] = lrelu(h1 @ W2 + b2); K=2048, S=16
  k_gemm3<<<dim3(16, 16), 256, 0, stream>>>(h1hi, h1lo, W2, P, 2048, 1024, 128);
  k_reduce<<<128, 256, 0, stream>>>(P, b2, h2hi, h2lo, 1024, 16);
  // L3: [128,1024] = lrelu(h2 @ W3 + b3); K=1024, S=8
  k_gemm3<<<dim3(16, 8), 256, 0, stream>>>(h2hi, h2lo, W3, P, 1024, 1024, 128);
  // L3 epilogue: h3hi plane + out[r] = h3 . Wc[:1024] + bc  (single writer)
  k_reduce3<<<128, 256, 0, stream>>>(P, b3, Wc, bc, h3hi, out);
  // M = h3 @ T, split-4 -> accM bf16 [4][128][10240] (640 blocks)
  k_gemm4<<<dim3(160, 4), 256, 0, stream>>>(h3hi, T, accM);
  // minibatch discrimination: atomicAdd o_b contributions into out
  k_pairwise<<<512, 512, 0, stream>>>(accM, Wc, out);
}